// Round 6
// baseline (226.065 us; speedup 1.0000x reference)
//
#include <hip/hip_runtime.h>
#include <stdint.h>

#define NB 2
#define NT 4096
#define NC 768
#define NH 12
#define ND 64
#define NBT (NB*NT)      // 8192
#define NQKV (3*NC)      // 2304

typedef _Float16 half_t;
typedef __attribute__((ext_vector_type(8))) _Float16 f16x8;
typedef __attribute__((ext_vector_type(4))) _Float16 f16x4;
typedef __attribute__((ext_vector_type(2))) __fp16 fp16x2;   // native type of cvt_pkrtz
typedef __attribute__((ext_vector_type(4))) float f32x4;

#define MFMA16(a,b,c) __builtin_amdgcn_mfma_f32_16x16x32_f16((a),(b),(c),0,0,0)

__device__ __forceinline__ void load_lds16(const void* g, void* l) {
    auto gp = reinterpret_cast<__attribute__((address_space(1))) char*>(reinterpret_cast<uintptr_t>(g));
    auto lp = reinterpret_cast<__attribute__((address_space(3))) char*>(reinterpret_cast<uintptr_t>(l));
    __builtin_amdgcn_global_load_lds(gp, lp, 16, 0, 0);
}

// ---------------- pack fp32 -> f16 (vectorized) ----------------
__global__ __launch_bounds__(256) void k_pack(const float* __restrict__ in, half_t* __restrict__ out, int n4) {
    int i = blockIdx.x * 256 + threadIdx.x;
    if (i >= n4) return;
    float4 f = reinterpret_cast<const float4*>(in)[i];
    f16x4 h;
    h[0] = (half_t)f.x; h[1] = (half_t)f.y; h[2] = (half_t)f.z; h[3] = (half_t)f.w;
    reinterpret_cast<f16x4*>(out)[i] = h;
}

// ---------------- pack + transpose: in[K][N] fp32 -> out[N][K] f16 ----------------
__global__ __launch_bounds__(256) void k_packT(const float* __restrict__ in, half_t* __restrict__ out, int N, int K) {
    int idx = blockIdx.x * 256 + threadIdx.x;
    if (idx >= N * K) return;
    int n = idx / K, k = idx - n * K;
    out[idx] = (half_t)in[(size_t)k * N + n];
}

// ---------------- GEMM: C[M][N] = A[M][K=768] * Bt[N][K=768]^T + bias ----------------
// R5: m97-pattern pipeline. Old loop was {barrier; stage; barrier; compute} -- the
// barrier right after the stage drains vmcnt with ZERO overlap, exposing full memory
// latency on every one of 24 k-steps. New loop: double-buffered LDS, stage(ks+1)
// issued BEFORE compute(ks), single barrier per step (the stage has the whole
// ds_read+MFMA phase to land before the drain catches stragglers).
template<int OUTF32>
__global__ __launch_bounds__(256) void k_gemm(const half_t* __restrict__ A, const half_t* __restrict__ Bt,
                                              const float* __restrict__ bias, void* __restrict__ out, int N) {
    __shared__ half_t As[2][128 * 32];
    __shared__ half_t Bs[2][128 * 32];
    const int tid = threadIdx.x;
    const int lane = tid & 63, w = tid >> 6;
    const int m0 = blockIdx.x * 128, n0 = blockIdx.y * 128;
    const int wm = (w >> 1) * 64, wn = (w & 1) * 64;
    const int lr = lane & 15, lk = (lane >> 4) * 8;

    f32x4 acc[4][4];
#pragma unroll
    for (int a = 0; a < 4; ++a)
#pragma unroll
        for (int bq = 0; bq < 4; ++bq) acc[a][bq] = (f32x4){0.f, 0.f, 0.f, 0.f};

    const int c0 = tid, c1 = 256 + tid;
    const int ldsbase = (tid & ~63) * 16;   // wave-uniform byte base for global_load_lds
    const half_t* A0 = A  + (size_t)(m0 + (c0 >> 2)) * NC + (c0 & 3) * 8;
    const half_t* A1 = A  + (size_t)(m0 + (c1 >> 2)) * NC + (c1 & 3) * 8;
    const half_t* B0 = Bt + (size_t)(n0 + (c0 >> 2)) * NC + (c0 & 3) * 8;
    const half_t* B1 = Bt + (size_t)(n0 + (c1 >> 2)) * NC + (c1 & 3) * 8;

    auto stage = [&](int buf, int k0) {
        load_lds16(A0 + k0, (char*)&As[buf][0] + ldsbase);
        load_lds16(B0 + k0, (char*)&Bs[buf][0] + ldsbase);
        load_lds16(A1 + k0, (char*)&As[buf][0] + 4096 + ldsbase);
        load_lds16(B1 + k0, (char*)&Bs[buf][0] + 4096 + ldsbase);
    };

    stage(0, 0);
    __syncthreads();
    int cur = 0;

    for (int ks = 0; ks < 24; ++ks) {
        if (ks < 23) stage(cur ^ 1, (ks + 1) * 32);
        f16x8 af[4], bf[4];
#pragma unroll
        for (int mi = 0; mi < 4; ++mi)
            af[mi] = *reinterpret_cast<const f16x8*>(&As[cur][(wm + mi * 16 + lr) * 32 + lk]);
#pragma unroll
        for (int ni = 0; ni < 4; ++ni)
            bf[ni] = *reinterpret_cast<const f16x8*>(&Bs[cur][(wn + ni * 16 + lr) * 32 + lk]);
#pragma unroll
        for (int mi = 0; mi < 4; ++mi)
#pragma unroll
            for (int ni = 0; ni < 4; ++ni)
                acc[mi][ni] = MFMA16(af[mi], bf[ni], acc[mi][ni]);
        __syncthreads();   // drains stage vmcnt (overlapped by compute) + fences buf reads
        cur ^= 1;
    }

    const int rg = (lane >> 4) * 4;   // C/D layout: row=(lane>>4)*4+i, col=lane&15
#pragma unroll
    for (int ni = 0; ni < 4; ++ni) {
        const int gn = n0 + wn + ni * 16 + lr;
        const float bv = bias[gn];
#pragma unroll
        for (int mi = 0; mi < 4; ++mi)
#pragma unroll
            for (int i = 0; i < 4; ++i) {
                const size_t gm = (size_t)(m0 + wm + mi * 16 + rg + i);
                const float v = acc[mi][ni][i] + bv;
                if (OUTF32) reinterpret_cast<float*>(out)[gm * N + gn] = v;
                else        reinterpret_cast<half_t*>(out)[gm * N + gn] = (half_t)v;
            }
    }
}

// ---------------- V repack: qkv[.,1536+h*64+d] -> Vt[bh][d][t] (LDS tile transpose) ----------------
__global__ __launch_bounds__(256) void k_vt(const half_t* __restrict__ qkv, half_t* __restrict__ Vt) {
    __shared__ half_t tile[64][72];
    const int tid = threadIdx.x;
    const int t0 = blockIdx.x * 64, bh = blockIdx.y;
    const int b = bh / NH, h = bh - b * NH;
    {
        const int tl = tid >> 2, dc = (tid & 3) * 16;
        const half_t* src = qkv + (size_t)(b * NT + t0 + tl) * NQKV + 2 * NC + h * ND + dc;
        f16x8 v0 = *reinterpret_cast<const f16x8*>(src);
        f16x8 v1 = *reinterpret_cast<const f16x8*>(src + 8);
        *reinterpret_cast<f16x8*>(&tile[tl][dc]) = v0;
        *reinterpret_cast<f16x8*>(&tile[tl][dc + 8]) = v1;
    }
    __syncthreads();
    {
        const int d = tid >> 2, tc = (tid & 3) * 16;
        half_t* dst = Vt + ((size_t)bh * ND + d) * NT + t0 + tc;
        f16x8 o0, o1;
#pragma unroll
        for (int j = 0; j < 8; ++j) o0[j] = tile[tc + j][d];
#pragma unroll
        for (int j = 0; j < 8; ++j) o1[j] = tile[tc + 8 + j][d];
        *reinterpret_cast<f16x8*>(dst) = o0;
        *reinterpret_cast<f16x8*>(dst + 8) = o1;
    }
}

// ---------------- Flash attention v10: v9 + fused per-qf softmax/PV chains ----------------
// R4 (v9) WIN: conflicts halved as predicted, 133->119us. Residual: phase-serialized
// iteration (QKT | all-32-exp2 | all-16-PV-MFMA) -- each y[qf] chain only needs its own
// 8 exp2, so fuse per qf: {exp2 x8 -> pack -> 4 MFMAs}, 4 independent chains; qf+1's
// exp2 (trans pipe) issues under qf's MFMAs. V-rows hoisted before softmax (independent
// of s) so their LDS latency hides under exp2. No new loop-carried state (no R2 spill
// mode; tripwire = FETCH_SIZE).
struct __align__(16) AttnSmem {
    union {
        struct { half_t K[2][64 * 64]; half_t V[2][64 * 64]; } m;   // 32 KB main
        struct { float y[2][64][64]; float l[2][64][4]; } r;        // 34 KB epilogue
    };
};

__global__ __launch_bounds__(256, 3) void k_attn(const half_t* __restrict__ qkv, const half_t* __restrict__ Vt,
                                                 half_t* __restrict__ Y) {
    __shared__ AttnSmem sm;
    const int tid = threadIdx.x, lane = tid & 63, w = tid >> 6;
    const int qw = w & 1, kw = w >> 1;
    const int lr = lane & 15, g = lane >> 4;
    const int qt = blockIdx.x, bh = blockIdx.y;
    const int b = bh / NH, h = bh - b * NH;
    const half_t* Qp = qkv + (size_t)b * NT * NQKV + h * ND;        // q cols
    const half_t* Kp = Qp + NC;                                     // k cols
    const half_t* Vbase = Vt + (size_t)bh * ND * NT;                // V^T [d][t]
    const int q0 = qt * 128 + qw * 64;

    // staging geometry: 256 threads x 16B = 4KB per instr = 32 rows of 128B; 2 instrs per 8KB tile
    const int sr = tid >> 3;                                   // row 0..31 (instr0), +32 (instr1)
    const int colh = (((tid & 7) << 3)) ^ ((sr & 7) << 3);     // swizzled source col (halfs)
    const int wub = (tid & ~63) * 16;                          // wave-uniform LDS byte base

    // Q fragments (B-operand: col=lr=q), 4 q-frags x 2 d-halves, pre-scaled by 1/sqrt(D)*log2(e)
    f16x8 aq[4][2];
    const half_t cch = (half_t)(0.125f * 1.4426950408889634f);
#pragma unroll
    for (int qf = 0; qf < 4; ++qf)
#pragma unroll
        for (int dh = 0; dh < 2; ++dh) {
            aq[qf][dh] = *reinterpret_cast<const f16x8*>(&Qp[(size_t)(q0 + qf * 16 + lr) * NQKV + dh * 32 + g * 8]);
#pragma unroll
            for (int j = 0; j < 8; ++j) aq[qf][dh][j] = aq[qf][dh][j] * cch;
        }

    // swizzled K-read columns (b128): row = st*16+lr, chunk ^= (lr&7)
    const int swk = (lr & 7) << 3;
    const int cA = (g * 8) ^ swk;          // d-chunk 0
    const int cB = (32 + g * 8) ^ swk;     // d-chunk 1
    // swizzled V-read columns (b64 pairs) for this wave's key-half (ks = kw)
    const int psw = lr & 7;
    const int goff = (g & 1) << 2;
    const int vcol[2] = { (((g >> 1) + 4 * kw + 0) ^ psw) * 8 + goff,
                          (((g >> 1) + 4 * kw + 2) ^ psw) * 8 + goff };

    f32x4 y[4][4];
#pragma unroll
    for (int qf = 0; qf < 4; ++qf)
#pragma unroll
        for (int df = 0; df < 4; ++df) y[qf][df] = (f32x4){0.f, 0.f, 0.f, 0.f};
    float l_[4] = {0.f, 0.f, 0.f, 0.f};

    auto stagebuf = [&](int buf, const half_t* Ks, const half_t* Vs) {
        char* kdst = (char*)&sm.m.K[buf][0] + wub;
        char* vdst = (char*)&sm.m.V[buf][0] + wub;
        load_lds16(Ks, kdst);
        load_lds16(Ks + (size_t)32 * NQKV, kdst + 4096);
        load_lds16(Vs, vdst);
        load_lds16(Vs + (size_t)32 * NT, vdst + 4096);
    };

    const half_t* ksrc = Kp + (size_t)sr * NQKV + colh;
    const half_t* vsrc = Vbase + (size_t)sr * NT + colh;
    stagebuf(0, ksrc, vsrc);
    ksrc += (size_t)64 * NQKV;
    vsrc += 64;
    __syncthreads();
    int cur = 0;
    const int stb = 2 * kw;

    for (int t = 0; t < NT / 64; ++t) {
        if (t < NT / 64 - 1) {
            stagebuf(cur ^ 1, ksrc, vsrc);
            ksrc += (size_t)64 * NQKV;
            vsrc += 64;
        }

        // ---- QK^T (swapped), this wave's 32-key half: s[qf][sl][i], st = stb+sl ----
        f32x4 s[4][2];
#pragma unroll
        for (int qf = 0; qf < 4; ++qf) { s[qf][0] = (f32x4){0.f,0.f,0.f,0.f}; s[qf][1] = (f32x4){0.f,0.f,0.f,0.f}; }
        const half_t* Kc = &sm.m.K[cur][0];
        __builtin_amdgcn_s_setprio(1);
#pragma unroll
        for (int sl = 0; sl < 2; ++sl) {
            const int row = (stb + sl) * 16 + lr;
            f16x8 bk0 = *reinterpret_cast<const f16x8*>(&Kc[row * 64 + cA]);
            s[0][sl] = MFMA16(bk0, aq[0][0], s[0][sl]);
            s[1][sl] = MFMA16(bk0, aq[1][0], s[1][sl]);
            s[2][sl] = MFMA16(bk0, aq[2][0], s[2][sl]);
            s[3][sl] = MFMA16(bk0, aq[3][0], s[3][sl]);
            f16x8 bk1 = *reinterpret_cast<const f16x8*>(&Kc[row * 64 + cB]);
            s[0][sl] = MFMA16(bk1, aq[0][1], s[0][sl]);
            s[1][sl] = MFMA16(bk1, aq[1][1], s[1][sl]);
            s[2][sl] = MFMA16(bk1, aq[2][1], s[2][sl]);
            s[3][sl] = MFMA16(bk1, aq[3][1], s[3][sl]);
        }
        __builtin_amdgcn_s_setprio(0);

        // ---- hoist V rows (independent of softmax; LDS latency hides under exp2) ----
        const half_t* Vc = &sm.m.V[cur][0];
        union { f16x8 v; f16x4 q[2]; } va[4];
#pragma unroll
        for (int df = 0; df < 4; ++df) {
            const half_t* vrow = &Vc[(df * 16 + lr) * 64];
            va[df].q[0] = *reinterpret_cast<const f16x4*>(vrow + vcol[0]);
            va[df].q[1] = *reinterpret_cast<const f16x4*>(vrow + vcol[1]);
        }

        // ---- fused per-qf softmax+PV: 4 independent {exp2 x8 -> pack -> 4 MFMA} chains ----
#pragma unroll
        for (int qf = 0; qf < 4; ++qf) {
            float ps = 0.f;
            union { f16x8 v; fp16x2 h[4]; } u;
#pragma unroll
            for (int hs = 0; hs < 2; ++hs) {   // hs: local st within this ks
                const float p0 = __builtin_amdgcn_exp2f(s[qf][hs][0]);
                const float p1 = __builtin_amdgcn_exp2f(s[qf][hs][1]);
                const float p2 = __builtin_amdgcn_exp2f(s[qf][hs][2]);
                const float p3 = __builtin_amdgcn_exp2f(s[qf][hs][3]);
                u.h[2 * hs]     = __builtin_amdgcn_cvt_pkrtz(p0, p1);
                u.h[2 * hs + 1] = __builtin_amdgcn_cvt_pkrtz(p2, p3);
                ps += (p0 + p1) + (p2 + p3);
            }
            l_[qf] += ps;
            __builtin_amdgcn_s_setprio(1);
            y[qf][0] = MFMA16(va[0].v, u.v, y[qf][0]);
            y[qf][1] = MFMA16(va[1].v, u.v, y[qf][1]);
            y[qf][2] = MFMA16(va[2].v, u.v, y[qf][2]);
            y[qf][3] = MFMA16(va[3].v, u.v, y[qf][3]);
            __builtin_amdgcn_s_setprio(0);
        }

        __syncthreads();   // drains stage vmcnt + all waves done reading buf[cur]
        cur ^= 1;
    }

    // ---- cross-wave (key-half) reduction: kw=1 publishes y/l, kw=0 combines+stores ----
    if (kw == 1) {
#pragma unroll
        for (int qf = 0; qf < 4; ++qf)
#pragma unroll
            for (int df = 0; df < 4; ++df) {
                const int jb = (qf * 16 + df * 4) ^ ((lane & 7) << 2);   // bank swizzle
                *reinterpret_cast<f32x4*>(&sm.r.y[qw][lane][jb]) = y[qf][df];
            }
#pragma unroll
        for (int qf = 0; qf < 4; ++qf) sm.r.l[qw][lane][qf] = l_[qf];
    }
    __syncthreads();
    if (kw == 0) {
#pragma unroll
        for (int qf = 0; qf < 4; ++qf) {
#pragma unroll
            for (int df = 0; df < 4; ++df) {
                const int jb = (qf * 16 + df * 4) ^ ((lane & 7) << 2);
                const f32x4 yp = *reinterpret_cast<const f32x4*>(&sm.r.y[qw][lane][jb]);
                y[qf][df] += yp;
            }
            float l = l_[qf] + sm.r.l[qw][lane][qf];
            l += __shfl_xor(l, 16);
            l += __shfl_xor(l, 32);
            const float rl = 1.f / l;
            half_t* Yp = Y + (size_t)(b * NT + q0 + qf * 16 + lr) * NC + h * ND + g * 4;
#pragma unroll
            for (int df = 0; df < 4; ++df) {
                union { f16x4 v; fp16x2 hh[2]; } o;
                o.hh[0] = __builtin_amdgcn_cvt_pkrtz(y[qf][df][0] * rl, y[qf][df][1] * rl);
                o.hh[1] = __builtin_amdgcn_cvt_pkrtz(y[qf][df][2] * rl, y[qf][df][3] * rl);
                *reinterpret_cast<f16x4*>(Yp + df * 16) = o.v;
            }
        }
    }
}

extern "C" void kernel_launch(void* const* d_in, const int* in_sizes, int n_in,
                              void* d_out, int out_size, void* d_ws, size_t ws_size,
                              hipStream_t stream) {
    const float* x  = (const float*)d_in[0];
    const float* Wa = (const float*)d_in[1];
    const float* ba = (const float*)d_in[2];
    const float* Wp = (const float*)d_in[3];
    const float* bp = (const float*)d_in[4];
    float* out = (float*)d_out;

    char* ws = (char*)d_ws;
    half_t* xh   = (half_t*)ws; ws += (size_t)NBT * NC * 2;
    half_t* Wat  = (half_t*)ws; ws += (size_t)NQKV * NC * 2;
    half_t* Wpt  = (half_t*)ws; ws += (size_t)NC * NC * 2;
    half_t* qkvh = (half_t*)ws; ws += (size_t)NBT * NQKV * 2;
    half_t* vt   = (half_t*)ws; ws += (size_t)NB * NH * ND * NT * 2;
    half_t* yh   = (half_t*)ws; ws += (size_t)NBT * NC * 2;

    k_pack<<<(NBT * NC / 4 + 255) / 256, 256, 0, stream>>>(x, xh, NBT * NC / 4);
    k_packT<<<(NQKV * NC + 255) / 256, 256, 0, stream>>>(Wa, Wat, NQKV, NC);
    k_packT<<<(NC * NC + 255) / 256, 256, 0, stream>>>(Wp, Wpt, NC, NC);
    k_gemm<0><<<dim3(NBT / 128, NQKV / 128), 256, 0, stream>>>(xh, Wat, ba, qkvh, NQKV);
    k_vt<<<dim3(NT / 64, NB * NH), 256, 0, stream>>>(qkvh, vt);
    k_attn<<<dim3(NT / 128, NB * NH), 256, 0, stream>>>(qkvh, vt, yh);
    k_gemm<1><<<dim3(NBT / 128, NC / 128), 256, 0, stream>>>(yh, Wpt, bp, out, NC);
}

// Round 7
// 195.167 us; speedup vs baseline: 1.1583x; 1.1583x over previous
//
#include <hip/hip_runtime.h>
#include <stdint.h>

#define NB 2
#define NT 4096
#define NC 768
#define NH 12
#define ND 64
#define NBT (NB*NT)      // 8192
#define NQKV (3*NC)      // 2304

typedef _Float16 half_t;
typedef __attribute__((ext_vector_type(8))) _Float16 f16x8;
typedef __attribute__((ext_vector_type(4))) _Float16 f16x4;
typedef __attribute__((ext_vector_type(2))) __fp16 fp16x2;   // native type of cvt_pkrtz
typedef __attribute__((ext_vector_type(4))) float f32x4;

#define MFMA16(a,b,c) __builtin_amdgcn_mfma_f32_16x16x32_f16((a),(b),(c),0,0,0)

__device__ __forceinline__ void load_lds16(const void* g, void* l) {
    auto gp = reinterpret_cast<__attribute__((address_space(1))) char*>(reinterpret_cast<uintptr_t>(g));
    auto lp = reinterpret_cast<__attribute__((address_space(3))) char*>(reinterpret_cast<uintptr_t>(l));
    __builtin_amdgcn_global_load_lds(gp, lp, 16, 0, 0);
}

// ---------------- prep: fused {pack x fp32->f16} + {tiled transpose Wa} + {tiled transpose Wp} ----------------
// R6: merged 3 launches into 1. Old k_packT read in[k*N+n] with consecutive lanes at
// stride N*4B (64 transactions/wave-load); now LDS 32x32 tile-transpose: coalesced
// float4 reads, coalesced f16x4 writes.
#define PACK_BLKS ((NBT * NC / 4) / 256)          // 6144
#define WA_TILES ((NC / 32) * (NQKV / 32))        // 24*72 = 1728
#define WP_TILES ((NC / 32) * (NC / 32))          // 24*24 = 576
#define PREP_BLKS (PACK_BLKS + WA_TILES + WP_TILES)

__global__ __launch_bounds__(256) void k_prep(const float* __restrict__ x, half_t* __restrict__ xh,
                                              const float* __restrict__ Wa, half_t* __restrict__ Wat,
                                              const float* __restrict__ Wp, half_t* __restrict__ Wpt) {
    const int bid = blockIdx.x, tid = threadIdx.x;
    if (bid < PACK_BLKS) {
        const int i = bid * 256 + tid;
        float4 f = reinterpret_cast<const float4*>(x)[i];
        f16x4 h;
        h[0] = (half_t)f.x; h[1] = (half_t)f.y; h[2] = (half_t)f.z; h[3] = (half_t)f.w;
        reinterpret_cast<f16x4*>(xh)[i] = h;
        return;
    }
    __shared__ half_t tile[32][36];
    const float* in; half_t* out; int N, kt, nt;
    if (bid < PACK_BLKS + WA_TILES) {
        const int t = bid - PACK_BLKS;
        in = Wa; out = Wat; N = NQKV;
        kt = t / (NQKV / 32); nt = t - kt * (NQKV / 32);
    } else {
        const int t = bid - PACK_BLKS - WA_TILES;
        in = Wp; out = Wpt; N = NC;
        kt = t / (NC / 32); nt = t - kt * (NC / 32);
    }
    const int k0 = kt * 32, n0 = nt * 32;
    {
        const int r = tid >> 3, c = (tid & 7) * 4;
        float4 f = *reinterpret_cast<const float4*>(&in[(size_t)(k0 + r) * N + n0 + c]);
        tile[r][c] = (half_t)f.x; tile[r][c + 1] = (half_t)f.y;
        tile[r][c + 2] = (half_t)f.z; tile[r][c + 3] = (half_t)f.w;
    }
    __syncthreads();
    {
        const int rn = tid >> 3, ck = (tid & 7) * 4;
        f16x4 u;
        u[0] = tile[ck][rn]; u[1] = tile[ck + 1][rn];
        u[2] = tile[ck + 2][rn]; u[3] = tile[ck + 3][rn];
        *reinterpret_cast<f16x4*>(&out[(size_t)(n0 + rn) * NC + k0 + ck]) = u;
    }
}

// ---------------- GEMM: C[M][N] = A[M][K=768] * Bt[N][K=768]^T + bias ----------------
// m97-pattern pipeline: double-buffered LDS, stage(ks+1) issued BEFORE compute(ks),
// single barrier per step (stage has the whole ds_read+MFMA phase to land).
template<int OUTF32>
__global__ __launch_bounds__(256) void k_gemm(const half_t* __restrict__ A, const half_t* __restrict__ Bt,
                                              const float* __restrict__ bias, void* __restrict__ out, int N) {
    __shared__ half_t As[2][128 * 32];
    __shared__ half_t Bs[2][128 * 32];
    const int tid = threadIdx.x;
    const int lane = tid & 63, w = tid >> 6;
    const int m0 = blockIdx.x * 128, n0 = blockIdx.y * 128;
    const int wm = (w >> 1) * 64, wn = (w & 1) * 64;
    const int lr = lane & 15, lk = (lane >> 4) * 8;

    f32x4 acc[4][4];
#pragma unroll
    for (int a = 0; a < 4; ++a)
#pragma unroll
        for (int bq = 0; bq < 4; ++bq) acc[a][bq] = (f32x4){0.f, 0.f, 0.f, 0.f};

    const int c0 = tid, c1 = 256 + tid;
    const int ldsbase = (tid & ~63) * 16;   // wave-uniform byte base for global_load_lds
    const half_t* A0 = A  + (size_t)(m0 + (c0 >> 2)) * NC + (c0 & 3) * 8;
    const half_t* A1 = A  + (size_t)(m0 + (c1 >> 2)) * NC + (c1 & 3) * 8;
    const half_t* B0 = Bt + (size_t)(n0 + (c0 >> 2)) * NC + (c0 & 3) * 8;
    const half_t* B1 = Bt + (size_t)(n0 + (c1 >> 2)) * NC + (c1 & 3) * 8;

    auto stage = [&](int buf, int k0) {
        load_lds16(A0 + k0, (char*)&As[buf][0] + ldsbase);
        load_lds16(B0 + k0, (char*)&Bs[buf][0] + ldsbase);
        load_lds16(A1 + k0, (char*)&As[buf][0] + 4096 + ldsbase);
        load_lds16(B1 + k0, (char*)&Bs[buf][0] + 4096 + ldsbase);
    };

    stage(0, 0);
    __syncthreads();
    int cur = 0;

    for (int ks = 0; ks < 24; ++ks) {
        if (ks < 23) stage(cur ^ 1, (ks + 1) * 32);
        f16x8 af[4], bf[4];
#pragma unroll
        for (int mi = 0; mi < 4; ++mi)
            af[mi] = *reinterpret_cast<const f16x8*>(&As[cur][(wm + mi * 16 + lr) * 32 + lk]);
#pragma unroll
        for (int ni = 0; ni < 4; ++ni)
            bf[ni] = *reinterpret_cast<const f16x8*>(&Bs[cur][(wn + ni * 16 + lr) * 32 + lk]);
#pragma unroll
        for (int mi = 0; mi < 4; ++mi)
#pragma unroll
            for (int ni = 0; ni < 4; ++ni)
                acc[mi][ni] = MFMA16(af[mi], bf[ni], acc[mi][ni]);
        __syncthreads();   // drains stage vmcnt (overlapped by compute) + fences buf reads
        cur ^= 1;
    }

    const int rg = (lane >> 4) * 4;   // C/D layout: row=(lane>>4)*4+i, col=lane&15
#pragma unroll
    for (int ni = 0; ni < 4; ++ni) {
        const int gn = n0 + wn + ni * 16 + lr;
        const float bv = bias[gn];
#pragma unroll
        for (int mi = 0; mi < 4; ++mi)
#pragma unroll
            for (int i = 0; i < 4; ++i) {
                const size_t gm = (size_t)(m0 + wm + mi * 16 + rg + i);
                const float v = acc[mi][ni][i] + bv;
                if (OUTF32) reinterpret_cast<float*>(out)[gm * N + gn] = v;
                else        reinterpret_cast<half_t*>(out)[gm * N + gn] = (half_t)v;
            }
    }
}

// ---------------- V repack: qkv[.,1536+h*64+d] -> Vt[bh][d][t] (LDS tile transpose) ----------------
__global__ __launch_bounds__(256) void k_vt(const half_t* __restrict__ qkv, half_t* __restrict__ Vt) {
    __shared__ half_t tile[64][72];
    const int tid = threadIdx.x;
    const int t0 = blockIdx.x * 64, bh = blockIdx.y;
    const int b = bh / NH, h = bh - b * NH;
    {
        const int tl = tid >> 2, dc = (tid & 3) * 16;
        const half_t* src = qkv + (size_t)(b * NT + t0 + tl) * NQKV + 2 * NC + h * ND + dc;
        f16x8 v0 = *reinterpret_cast<const f16x8*>(src);
        f16x8 v1 = *reinterpret_cast<const f16x8*>(src + 8);
        *reinterpret_cast<f16x8*>(&tile[tl][dc]) = v0;
        *reinterpret_cast<f16x8*>(&tile[tl][dc + 8]) = v1;
    }
    __syncthreads();
    {
        const int d = tid >> 2, tc = (tid & 3) * 16;
        half_t* dst = Vt + ((size_t)bh * ND + d) * NT + t0 + tc;
        f16x8 o0, o1;
#pragma unroll
        for (int j = 0; j < 8; ++j) o0[j] = tile[tc + j][d];
#pragma unroll
        for (int j = 0; j < 8; ++j) o1[j] = tile[tc + 8 + j][d];
        *reinterpret_cast<f16x8*>(dst) = o0;
        *reinterpret_cast<f16x8*>(dst + 8) = o1;
    }
}

// ---------------- Flash attention v9 (reverted from v10): q=64/wave AND 12 waves/CU ----------------
// Ledger: R0 8w-split regressed (too little work/wave/barrier); R1 counted-vmcnt neutral;
// R2 score-lookahead spilled (FETCH 10x); R3 q=64 @ 6 waves/CU: conflicts halved but
// latency-exposed; R4 (this) = q=64 + 12 waves/CU: WIN 133->119us. R5 per-qf softmax/PV
// fusion REGRESSED 119->139 (broke phase-level ILP: 32 back-to-back exp2 saturate trans
// pipe, 16 ready-input MFMAs burst; short fused chains exposed latency 4x + setprio
// fences). Keep phases monolithic.
struct __align__(16) AttnSmem {
    union {
        struct { half_t K[2][64 * 64]; half_t V[2][64 * 64]; } m;   // 32 KB main
        struct { float y[2][64][64]; float l[2][64][4]; } r;        // 34 KB epilogue
    };
};

__global__ __launch_bounds__(256, 3) void k_attn(const half_t* __restrict__ qkv, const half_t* __restrict__ Vt,
                                                 half_t* __restrict__ Y) {
    __shared__ AttnSmem sm;
    const int tid = threadIdx.x, lane = tid & 63, w = tid >> 6;
    const int qw = w & 1, kw = w >> 1;
    const int lr = lane & 15, g = lane >> 4;
    const int qt = blockIdx.x, bh = blockIdx.y;
    const int b = bh / NH, h = bh - b * NH;
    const half_t* Qp = qkv + (size_t)b * NT * NQKV + h * ND;        // q cols
    const half_t* Kp = Qp + NC;                                     // k cols
    const half_t* Vbase = Vt + (size_t)bh * ND * NT;                // V^T [d][t]
    const int q0 = qt * 128 + qw * 64;

    // staging geometry: 256 threads x 16B = 4KB per instr = 32 rows of 128B; 2 instrs per 8KB tile
    const int sr = tid >> 3;                                   // row 0..31 (instr0), +32 (instr1)
    const int colh = (((tid & 7) << 3)) ^ ((sr & 7) << 3);     // swizzled source col (halfs)
    const int wub = (tid & ~63) * 16;                          // wave-uniform LDS byte base

    // Q fragments (B-operand: col=lr=q), 4 q-frags x 2 d-halves, pre-scaled by 1/sqrt(D)*log2(e)
    f16x8 aq[4][2];
    const half_t cch = (half_t)(0.125f * 1.4426950408889634f);
#pragma unroll
    for (int qf = 0; qf < 4; ++qf)
#pragma unroll
        for (int dh = 0; dh < 2; ++dh) {
            aq[qf][dh] = *reinterpret_cast<const f16x8*>(&Qp[(size_t)(q0 + qf * 16 + lr) * NQKV + dh * 32 + g * 8]);
#pragma unroll
            for (int j = 0; j < 8; ++j) aq[qf][dh][j] = aq[qf][dh][j] * cch;
        }

    // swizzled K-read columns (b128): row = st*16+lr, chunk ^= (lr&7)
    const int swk = (lr & 7) << 3;
    const int cA = (g * 8) ^ swk;          // d-chunk 0
    const int cB = (32 + g * 8) ^ swk;     // d-chunk 1
    // swizzled V-read columns (b64 pairs) for this wave's key-half (ks = kw)
    const int psw = lr & 7;
    const int goff = (g & 1) << 2;
    const int vcol[2] = { (((g >> 1) + 4 * kw + 0) ^ psw) * 8 + goff,
                          (((g >> 1) + 4 * kw + 2) ^ psw) * 8 + goff };

    f32x4 y[4][4];
#pragma unroll
    for (int qf = 0; qf < 4; ++qf)
#pragma unroll
        for (int df = 0; df < 4; ++df) y[qf][df] = (f32x4){0.f, 0.f, 0.f, 0.f};
    float l_[4] = {0.f, 0.f, 0.f, 0.f};

    auto stagebuf = [&](int buf, const half_t* Ks, const half_t* Vs) {
        char* kdst = (char*)&sm.m.K[buf][0] + wub;
        char* vdst = (char*)&sm.m.V[buf][0] + wub;
        load_lds16(Ks, kdst);
        load_lds16(Ks + (size_t)32 * NQKV, kdst + 4096);
        load_lds16(Vs, vdst);
        load_lds16(Vs + (size_t)32 * NT, vdst + 4096);
    };

    const half_t* ksrc = Kp + (size_t)sr * NQKV + colh;
    const half_t* vsrc = Vbase + (size_t)sr * NT + colh;
    stagebuf(0, ksrc, vsrc);
    ksrc += (size_t)64 * NQKV;
    vsrc += 64;
    __syncthreads();
    int cur = 0;
    const int stb = 2 * kw;

    for (int t = 0; t < NT / 64; ++t) {
        if (t < NT / 64 - 1) {
            stagebuf(cur ^ 1, ksrc, vsrc);
            ksrc += (size_t)64 * NQKV;
            vsrc += 64;
        }

        // ---- QK^T (swapped), this wave's 32-key half: s[qf][sl][i], st = stb+sl ----
        f32x4 s[4][2];
#pragma unroll
        for (int qf = 0; qf < 4; ++qf) { s[qf][0] = (f32x4){0.f,0.f,0.f,0.f}; s[qf][1] = (f32x4){0.f,0.f,0.f,0.f}; }
        const half_t* Kc = &sm.m.K[cur][0];
        __builtin_amdgcn_s_setprio(1);
#pragma unroll
        for (int sl = 0; sl < 2; ++sl) {
            const int row = (stb + sl) * 16 + lr;
            f16x8 bk0 = *reinterpret_cast<const f16x8*>(&Kc[row * 64 + cA]);
            s[0][sl] = MFMA16(bk0, aq[0][0], s[0][sl]);
            s[1][sl] = MFMA16(bk0, aq[1][0], s[1][sl]);
            s[2][sl] = MFMA16(bk0, aq[2][0], s[2][sl]);
            s[3][sl] = MFMA16(bk0, aq[3][0], s[3][sl]);
            f16x8 bk1 = *reinterpret_cast<const f16x8*>(&Kc[row * 64 + cB]);
            s[0][sl] = MFMA16(bk1, aq[0][1], s[0][sl]);
            s[1][sl] = MFMA16(bk1, aq[1][1], s[1][sl]);
            s[2][sl] = MFMA16(bk1, aq[2][1], s[2][sl]);
            s[3][sl] = MFMA16(bk1, aq[3][1], s[3][sl]);
        }
        __builtin_amdgcn_s_setprio(0);

        // ---- no-max softmax + lane-local pack: pb[qf] = packed p for this key-half ----
        f16x8 pb[4];
#pragma unroll
        for (int qf = 0; qf < 4; ++qf) {
            float ps = 0.f;
            union { f16x8 v; fp16x2 h[4]; } u;
#pragma unroll
            for (int hs = 0; hs < 2; ++hs) {   // hs: local st within this ks
                const float p0 = __builtin_amdgcn_exp2f(s[qf][hs][0]);
                const float p1 = __builtin_amdgcn_exp2f(s[qf][hs][1]);
                const float p2 = __builtin_amdgcn_exp2f(s[qf][hs][2]);
                const float p3 = __builtin_amdgcn_exp2f(s[qf][hs][3]);
                u.h[2 * hs]     = __builtin_amdgcn_cvt_pkrtz(p0, p1);
                u.h[2 * hs + 1] = __builtin_amdgcn_cvt_pkrtz(p2, p3);
                ps += (p0 + p1) + (p2 + p3);
            }
            pb[qf] = u.v;
            l_[qf] += ps;
        }

        // ---- PV (ks = kw): A = V^T rows, B = pb (register) ----
        const half_t* Vc = &sm.m.V[cur][0];
        __builtin_amdgcn_s_setprio(1);
#pragma unroll
        for (int df = 0; df < 4; ++df) {
            const half_t* vrow = &Vc[(df * 16 + lr) * 64];
            union { f16x8 v; f16x4 q[2]; } va;
            va.q[0] = *reinterpret_cast<const f16x4*>(vrow + vcol[0]);
            va.q[1] = *reinterpret_cast<const f16x4*>(vrow + vcol[1]);
            y[0][df] = MFMA16(va.v, pb[0], y[0][df]);
            y[1][df] = MFMA16(va.v, pb[1], y[1][df]);
            y[2][df] = MFMA16(va.v, pb[2], y[2][df]);
            y[3][df] = MFMA16(va.v, pb[3], y[3][df]);
        }
        __builtin_amdgcn_s_setprio(0);

        __syncthreads();   // drains stage vmcnt + all waves done reading buf[cur]
        cur ^= 1;
    }

    // ---- cross-wave (key-half) reduction: kw=1 publishes y/l, kw=0 combines+stores ----
    if (kw == 1) {
#pragma unroll
        for (int qf = 0; qf < 4; ++qf)
#pragma unroll
            for (int df = 0; df < 4; ++df) {
                const int jb = (qf * 16 + df * 4) ^ ((lane & 7) << 2);   // bank swizzle
                *reinterpret_cast<f32x4*>(&sm.r.y[qw][lane][jb]) = y[qf][df];
            }
#pragma unroll
        for (int qf = 0; qf < 4; ++qf) sm.r.l[qw][lane][qf] = l_[qf];
    }
    __syncthreads();
    if (kw == 0) {
#pragma unroll
        for (int qf = 0; qf < 4; ++qf) {
#pragma unroll
            for (int df = 0; df < 4; ++df) {
                const int jb = (qf * 16 + df * 4) ^ ((lane & 7) << 2);
                const f32x4 yp = *reinterpret_cast<const f32x4*>(&sm.r.y[qw][lane][jb]);
                y[qf][df] += yp;
            }
            float l = l_[qf] + sm.r.l[qw][lane][qf];
            l += __shfl_xor(l, 16);
            l += __shfl_xor(l, 32);
            const float rl = 1.f / l;
            half_t* Yp = Y + (size_t)(b * NT + q0 + qf * 16 + lr) * NC + h * ND + g * 4;
#pragma unroll
            for (int df = 0; df < 4; ++df) {
                union { f16x4 v; fp16x2 hh[2]; } o;
                o.hh[0] = __builtin_amdgcn_cvt_pkrtz(y[qf][df][0] * rl, y[qf][df][1] * rl);
                o.hh[1] = __builtin_amdgcn_cvt_pkrtz(y[qf][df][2] * rl, y[qf][df][3] * rl);
                *reinterpret_cast<f16x4*>(Yp + df * 16) = o.v;
            }
        }
    }
}

extern "C" void kernel_launch(void* const* d_in, const int* in_sizes, int n_in,
                              void* d_out, int out_size, void* d_ws, size_t ws_size,
                              hipStream_t stream) {
    const float* x  = (const float*)d_in[0];
    const float* Wa = (const float*)d_in[1];
    const float* ba = (const float*)d_in[2];
    const float* Wp = (const float*)d_in[3];
    const float* bp = (const float*)d_in[4];
    float* out = (float*)d_out;

    char* ws = (char*)d_ws;
    half_t* xh   = (half_t*)ws; ws += (size_t)NBT * NC * 2;
    half_t* Wat  = (half_t*)ws; ws += (size_t)NQKV * NC * 2;
    half_t* Wpt  = (half_t*)ws; ws += (size_t)NC * NC * 2;
    half_t* qkvh = (half_t*)ws; ws += (size_t)NBT * NQKV * 2;
    half_t* vt   = (half_t*)ws; ws += (size_t)NB * NH * ND * NT * 2;
    half_t* yh   = (half_t*)ws; ws += (size_t)NBT * NC * 2;

    k_prep<<<PREP_BLKS, 256, 0, stream>>>(x, xh, Wa, Wat, Wp, Wpt);
    k_gemm<0><<<dim3(NBT / 128, NQKV / 128), 256, 0, stream>>>(xh, Wat, ba, qkvh, NQKV);
    k_vt<<<dim3(NT / 64, NB * NH), 256, 0, stream>>>(qkvh, vt);
    k_attn<<<dim3(NT / 128, NB * NH), 256, 0, stream>>>(qkvh, vt, yh);
    k_gemm<1><<<dim3(NBT / 128, NC / 128), 256, 0, stream>>>(yh, Wpt, bp, out, NC);
}

// Round 8
// 194.343 us; speedup vs baseline: 1.1632x; 1.0042x over previous
//
#include <hip/hip_runtime.h>
#include <stdint.h>

#define NB 2
#define NT 4096
#define NC 768
#define NH 12
#define ND 64
#define NBT (NB*NT)      // 8192
#define NQKV (3*NC)      // 2304

typedef _Float16 half_t;
typedef __attribute__((ext_vector_type(8))) _Float16 f16x8;
typedef __attribute__((ext_vector_type(4))) _Float16 f16x4;
typedef __attribute__((ext_vector_type(2))) __fp16 fp16x2;   // native type of cvt_pkrtz
typedef __attribute__((ext_vector_type(4))) float f32x4;

#define MFMA16(a,b,c) __builtin_amdgcn_mfma_f32_16x16x32_f16((a),(b),(c),0,0,0)

__device__ __forceinline__ void load_lds16(const void* g, void* l) {
    auto gp = reinterpret_cast<__attribute__((address_space(1))) char*>(reinterpret_cast<uintptr_t>(g));
    auto lp = reinterpret_cast<__attribute__((address_space(3))) char*>(reinterpret_cast<uintptr_t>(l));
    __builtin_amdgcn_global_load_lds(gp, lp, 16, 0, 0);
}

// ---------------- prep: fused {pack x fp32->f16} + {tiled transpose Wa} + {tiled transpose Wp} ----------------
#define PACK_BLKS ((NBT * NC / 4) / 256)          // 6144
#define WA_TILES ((NC / 32) * (NQKV / 32))        // 24*72 = 1728
#define WP_TILES ((NC / 32) * (NC / 32))          // 24*24 = 576
#define PREP_BLKS (PACK_BLKS + WA_TILES + WP_TILES)

__global__ __launch_bounds__(256) void k_prep(const float* __restrict__ x, half_t* __restrict__ xh,
                                              const float* __restrict__ Wa, half_t* __restrict__ Wat,
                                              const float* __restrict__ Wp, half_t* __restrict__ Wpt) {
    const int bid = blockIdx.x, tid = threadIdx.x;
    if (bid < PACK_BLKS) {
        const int i = bid * 256 + tid;
        float4 f = reinterpret_cast<const float4*>(x)[i];
        f16x4 h;
        h[0] = (half_t)f.x; h[1] = (half_t)f.y; h[2] = (half_t)f.z; h[3] = (half_t)f.w;
        reinterpret_cast<f16x4*>(xh)[i] = h;
        return;
    }
    __shared__ half_t tile[32][36];
    const float* in; half_t* out; int N, kt, nt;
    if (bid < PACK_BLKS + WA_TILES) {
        const int t = bid - PACK_BLKS;
        in = Wa; out = Wat; N = NQKV;
        kt = t / (NQKV / 32); nt = t - kt * (NQKV / 32);
    } else {
        const int t = bid - PACK_BLKS - WA_TILES;
        in = Wp; out = Wpt; N = NC;
        kt = t / (NC / 32); nt = t - kt * (NC / 32);
    }
    const int k0 = kt * 32, n0 = nt * 32;
    {
        const int r = tid >> 3, c = (tid & 7) * 4;
        float4 f = *reinterpret_cast<const float4*>(&in[(size_t)(k0 + r) * N + n0 + c]);
        tile[r][c] = (half_t)f.x; tile[r][c + 1] = (half_t)f.y;
        tile[r][c + 2] = (half_t)f.z; tile[r][c + 3] = (half_t)f.w;
    }
    __syncthreads();
    {
        const int rn = tid >> 3, ck = (tid & 7) * 4;
        f16x4 u;
        u[0] = tile[ck][rn]; u[1] = tile[ck + 1][rn];
        u[2] = tile[ck + 2][rn]; u[3] = tile[ck + 3][rn];
        *reinterpret_cast<f16x4*>(&out[(size_t)(n0 + rn) * NC + k0 + ck]) = u;
    }
}

// ---------------- GEMM: C[M][N] = A[M][K=768] * Bt[N][K=768]^T + bias ----------------
// m97-pattern pipeline: double-buffered LDS, stage(ks+1) issued BEFORE compute(ks),
// single barrier per step. R7: V-part blocks of GEMM0 (n0 >= 1536, Vt != null) write
// Vt[bh][d][t] directly via wave-local LDS transpose (k_vt kernel deleted): each wave's
// 64x64 C-tile = one head (V0 = n0-1536+wn is 64-aligned) x 64 t-rows. LDS cell for
// (d, t): q[d*64 + (t ^ ((d&7)<<3))] -- XOR bits 3-5 only; 4-runs (write, t0%4==0) and
// 8-runs (read, tt%8==0) never cross the XOR bits, so vector ops stay contiguous.
// Stores: 8 instrs x {8 rows x 8 lanes x 16B = 128B-chunks} = coalesced.
template<int OUTF32>
__global__ __launch_bounds__(256) void k_gemm(const half_t* __restrict__ A, const half_t* __restrict__ Bt,
                                              const float* __restrict__ bias, void* __restrict__ out, int N,
                                              half_t* __restrict__ Vt) {
    __shared__ half_t As[2][128 * 32];
    __shared__ half_t Bs[2][128 * 32];
    const int tid = threadIdx.x;
    const int lane = tid & 63, w = tid >> 6;
    const int m0 = blockIdx.x * 128, n0 = blockIdx.y * 128;
    const int wm = (w >> 1) * 64, wn = (w & 1) * 64;
    const int lr = lane & 15, lk = (lane >> 4) * 8;

    f32x4 acc[4][4];
#pragma unroll
    for (int a = 0; a < 4; ++a)
#pragma unroll
        for (int bq = 0; bq < 4; ++bq) acc[a][bq] = (f32x4){0.f, 0.f, 0.f, 0.f};

    const int c0 = tid, c1 = 256 + tid;
    const int ldsbase = (tid & ~63) * 16;   // wave-uniform byte base for global_load_lds
    const half_t* A0 = A  + (size_t)(m0 + (c0 >> 2)) * NC + (c0 & 3) * 8;
    const half_t* A1 = A  + (size_t)(m0 + (c1 >> 2)) * NC + (c1 & 3) * 8;
    const half_t* B0 = Bt + (size_t)(n0 + (c0 >> 2)) * NC + (c0 & 3) * 8;
    const half_t* B1 = Bt + (size_t)(n0 + (c1 >> 2)) * NC + (c1 & 3) * 8;

    auto stage = [&](int buf, int k0) {
        load_lds16(A0 + k0, (char*)&As[buf][0] + ldsbase);
        load_lds16(B0 + k0, (char*)&Bs[buf][0] + ldsbase);
        load_lds16(A1 + k0, (char*)&As[buf][0] + 4096 + ldsbase);
        load_lds16(B1 + k0, (char*)&Bs[buf][0] + 4096 + ldsbase);
    };

    stage(0, 0);
    __syncthreads();
    int cur = 0;

    for (int ks = 0; ks < 24; ++ks) {
        if (ks < 23) stage(cur ^ 1, (ks + 1) * 32);
        f16x8 af[4], bf[4];
#pragma unroll
        for (int mi = 0; mi < 4; ++mi)
            af[mi] = *reinterpret_cast<const f16x8*>(&As[cur][(wm + mi * 16 + lr) * 32 + lk]);
#pragma unroll
        for (int ni = 0; ni < 4; ++ni)
            bf[ni] = *reinterpret_cast<const f16x8*>(&Bs[cur][(wn + ni * 16 + lr) * 32 + lk]);
#pragma unroll
        for (int mi = 0; mi < 4; ++mi)
#pragma unroll
            for (int ni = 0; ni < 4; ++ni)
                acc[mi][ni] = MFMA16(af[mi], bf[ni], acc[mi][ni]);
        __syncthreads();   // drains stage vmcnt (overlapped by compute) + fences buf reads
        cur ^= 1;
    }

    const int rg = (lane >> 4) * 4;   // C/D layout: row=(lane>>4)*4+i, col=lane&15

    if (Vt != nullptr && n0 >= 2 * NC) {
        // ---- V-part: transpose 64x64 wave tile in LDS, write Vt[bh][d][t] coalesced ----
        half_t* q = (w < 2) ? &As[w][0] : &Bs[w - 2][0];   // 8KB quadrant per wave
#pragma unroll
        for (int ni = 0; ni < 4; ++ni) {
            const int d = ni * 16 + lr;                      // col within wave tile = d
            const float bv = bias[n0 + wn + d];
            const int xsw = (d & 7) << 3;
#pragma unroll
            for (int mi = 0; mi < 4; ++mi) {
                const int t0 = mi * 16 + rg;                 // 4-aligned
                union { f16x4 v; fp16x2 hh[2]; } o;
                o.hh[0] = __builtin_amdgcn_cvt_pkrtz(acc[mi][ni][0] + bv, acc[mi][ni][1] + bv);
                o.hh[1] = __builtin_amdgcn_cvt_pkrtz(acc[mi][ni][2] + bv, acc[mi][ni][3] + bv);
                *reinterpret_cast<f16x4*>(&q[d * 64 + (t0 ^ xsw)]) = o.v;
            }
        }
        __syncthreads();
        const int M0 = m0 + wm;
        const int bh = (M0 >> 12) * NH + ((n0 - 2 * NC + wn) >> 6);
        half_t* vbase = Vt + (size_t)bh * ND * NT + (M0 & (NT - 1));
#pragma unroll
        for (int k2 = 0; k2 < 8; ++k2) {
            const int d = 8 * k2 + (lane >> 3);
            const int tt = (lane & 7) * 8;                   // 8-aligned
            f16x8 val = *reinterpret_cast<const f16x8*>(&q[d * 64 + (tt ^ ((d & 7) << 3))]);
            *reinterpret_cast<f16x8*>(&vbase[(size_t)d * NT + tt]) = val;
        }
        return;
    }

#pragma unroll
    for (int ni = 0; ni < 4; ++ni) {
        const int gn = n0 + wn + ni * 16 + lr;
        const float bv = bias[gn];
#pragma unroll
        for (int mi = 0; mi < 4; ++mi)
#pragma unroll
            for (int i = 0; i < 4; ++i) {
                const size_t gm = (size_t)(m0 + wm + mi * 16 + rg + i);
                const float v = acc[mi][ni][i] + bv;
                if (OUTF32) reinterpret_cast<float*>(out)[gm * N + gn] = v;
                else        reinterpret_cast<half_t*>(out)[gm * N + gn] = (half_t)v;
            }
    }
}

// ---------------- Flash attention v9: q=64/wave AND 12 waves/CU (qw x kw wave grid) ----------------
// Ledger: R0 8w-split regressed (too little work/wave/barrier); R1 counted-vmcnt neutral;
// R2 score-lookahead spilled (FETCH 10x); R3 q=64 @ 6 waves/CU: conflicts halved but
// latency-exposed; R4 = q=64 + 12 waves/CU: WIN 133->119us. R5 per-qf softmax/PV fusion
// REGRESSED (broke phase-level ILP). Keep phases monolithic; structure frozen at v9.
struct __align__(16) AttnSmem {
    union {
        struct { half_t K[2][64 * 64]; half_t V[2][64 * 64]; } m;   // 32 KB main
        struct { float y[2][64][64]; float l[2][64][4]; } r;        // 34 KB epilogue
    };
};

__global__ __launch_bounds__(256, 3) void k_attn(const half_t* __restrict__ qkv, const half_t* __restrict__ Vt,
                                                 half_t* __restrict__ Y) {
    __shared__ AttnSmem sm;
    const int tid = threadIdx.x, lane = tid & 63, w = tid >> 6;
    const int qw = w & 1, kw = w >> 1;
    const int lr = lane & 15, g = lane >> 4;
    const int qt = blockIdx.x, bh = blockIdx.y;
    const int b = bh / NH, h = bh - b * NH;
    const half_t* Qp = qkv + (size_t)b * NT * NQKV + h * ND;        // q cols
    const half_t* Kp = Qp + NC;                                     // k cols
    const half_t* Vbase = Vt + (size_t)bh * ND * NT;                // V^T [d][t]
    const int q0 = qt * 128 + qw * 64;

    // staging geometry: 256 threads x 16B = 4KB per instr = 32 rows of 128B; 2 instrs per 8KB tile
    const int sr = tid >> 3;                                   // row 0..31 (instr0), +32 (instr1)
    const int colh = (((tid & 7) << 3)) ^ ((sr & 7) << 3);     // swizzled source col (halfs)
    const int wub = (tid & ~63) * 16;                          // wave-uniform LDS byte base

    // Q fragments (B-operand: col=lr=q), 4 q-frags x 2 d-halves, pre-scaled by 1/sqrt(D)*log2(e)
    f16x8 aq[4][2];
    const half_t cch = (half_t)(0.125f * 1.4426950408889634f);
#pragma unroll
    for (int qf = 0; qf < 4; ++qf)
#pragma unroll
        for (int dh = 0; dh < 2; ++dh) {
            aq[qf][dh] = *reinterpret_cast<const f16x8*>(&Qp[(size_t)(q0 + qf * 16 + lr) * NQKV + dh * 32 + g * 8]);
#pragma unroll
            for (int j = 0; j < 8; ++j) aq[qf][dh][j] = aq[qf][dh][j] * cch;
        }

    // swizzled K-read columns (b128): row = st*16+lr, chunk ^= (lr&7)
    const int swk = (lr & 7) << 3;
    const int cA = (g * 8) ^ swk;          // d-chunk 0
    const int cB = (32 + g * 8) ^ swk;     // d-chunk 1
    // swizzled V-read columns (b64 pairs) for this wave's key-half (ks = kw)
    const int psw = lr & 7;
    const int goff = (g & 1) << 2;
    const int vcol[2] = { (((g >> 1) + 4 * kw + 0) ^ psw) * 8 + goff,
                          (((g >> 1) + 4 * kw + 2) ^ psw) * 8 + goff };

    f32x4 y[4][4];
#pragma unroll
    for (int qf = 0; qf < 4; ++qf)
#pragma unroll
        for (int df = 0; df < 4; ++df) y[qf][df] = (f32x4){0.f, 0.f, 0.f, 0.f};
    float l_[4] = {0.f, 0.f, 0.f, 0.f};

    auto stagebuf = [&](int buf, const half_t* Ks, const half_t* Vs) {
        char* kdst = (char*)&sm.m.K[buf][0] + wub;
        char* vdst = (char*)&sm.m.V[buf][0] + wub;
        load_lds16(Ks, kdst);
        load_lds16(Ks + (size_t)32 * NQKV, kdst + 4096);
        load_lds16(Vs, vdst);
        load_lds16(Vs + (size_t)32 * NT, vdst + 4096);
    };

    const half_t* ksrc = Kp + (size_t)sr * NQKV + colh;
    const half_t* vsrc = Vbase + (size_t)sr * NT + colh;
    stagebuf(0, ksrc, vsrc);
    ksrc += (size_t)64 * NQKV;
    vsrc += 64;
    __syncthreads();
    int cur = 0;
    const int stb = 2 * kw;

    for (int t = 0; t < NT / 64; ++t) {
        if (t < NT / 64 - 1) {
            stagebuf(cur ^ 1, ksrc, vsrc);
            ksrc += (size_t)64 * NQKV;
            vsrc += 64;
        }

        // ---- QK^T (swapped), this wave's 32-key half: s[qf][sl][i], st = stb+sl ----
        f32x4 s[4][2];
#pragma unroll
        for (int qf = 0; qf < 4; ++qf) { s[qf][0] = (f32x4){0.f,0.f,0.f,0.f}; s[qf][1] = (f32x4){0.f,0.f,0.f,0.f}; }
        const half_t* Kc = &sm.m.K[cur][0];
        __builtin_amdgcn_s_setprio(1);
#pragma unroll
        for (int sl = 0; sl < 2; ++sl) {
            const int row = (stb + sl) * 16 + lr;
            f16x8 bk0 = *reinterpret_cast<const f16x8*>(&Kc[row * 64 + cA]);
            s[0][sl] = MFMA16(bk0, aq[0][0], s[0][sl]);
            s[1][sl] = MFMA16(bk0, aq[1][0], s[1][sl]);
            s[2][sl] = MFMA16(bk0, aq[2][0], s[2][sl]);
            s[3][sl] = MFMA16(bk0, aq[3][0], s[3][sl]);
            f16x8 bk1 = *reinterpret_cast<const f16x8*>(&Kc[row * 64 + cB]);
            s[0][sl] = MFMA16(bk1, aq[0][1], s[0][sl]);
            s[1][sl] = MFMA16(bk1, aq[1][1], s[1][sl]);
            s[2][sl] = MFMA16(bk1, aq[2][1], s[2][sl]);
            s[3][sl] = MFMA16(bk1, aq[3][1], s[3][sl]);
        }
        __builtin_amdgcn_s_setprio(0);

        // ---- no-max softmax + lane-local pack: pb[qf] = packed p for this key-half ----
        f16x8 pb[4];
#pragma unroll
        for (int qf = 0; qf < 4; ++qf) {
            float ps = 0.f;
            union { f16x8 v; fp16x2 h[4]; } u;
#pragma unroll
            for (int hs = 0; hs < 2; ++hs) {   // hs: local st within this ks
                const float p0 = __builtin_amdgcn_exp2f(s[qf][hs][0]);
                const float p1 = __builtin_amdgcn_exp2f(s[qf][hs][1]);
                const float p2 = __builtin_amdgcn_exp2f(s[qf][hs][2]);
                const float p3 = __builtin_amdgcn_exp2f(s[qf][hs][3]);
                u.h[2 * hs]     = __builtin_amdgcn_cvt_pkrtz(p0, p1);
                u.h[2 * hs + 1] = __builtin_amdgcn_cvt_pkrtz(p2, p3);
                ps += (p0 + p1) + (p2 + p3);
            }
            pb[qf] = u.v;
            l_[qf] += ps;
        }

        // ---- PV (ks = kw): A = V^T rows, B = pb (register) ----
        const half_t* Vc = &sm.m.V[cur][0];
        __builtin_amdgcn_s_setprio(1);
#pragma unroll
        for (int df = 0; df < 4; ++df) {
            const half_t* vrow = &Vc[(df * 16 + lr) * 64];
            union { f16x8 v; f16x4 q[2]; } va;
            va.q[0] = *reinterpret_cast<const f16x4*>(vrow + vcol[0]);
            va.q[1] = *reinterpret_cast<const f16x4*>(vrow + vcol[1]);
            y[0][df] = MFMA16(va.v, pb[0], y[0][df]);
            y[1][df] = MFMA16(va.v, pb[1], y[1][df]);
            y[2][df] = MFMA16(va.v, pb[2], y[2][df]);
            y[3][df] = MFMA16(va.v, pb[3], y[3][df]);
        }
        __builtin_amdgcn_s_setprio(0);

        __syncthreads();   // drains stage vmcnt + all waves done reading buf[cur]
        cur ^= 1;
    }

    // ---- cross-wave (key-half) reduction: kw=1 publishes y/l, kw=0 combines+stores ----
    if (kw == 1) {
#pragma unroll
        for (int qf = 0; qf < 4; ++qf)
#pragma unroll
            for (int df = 0; df < 4; ++df) {
                const int jb = (qf * 16 + df * 4) ^ ((lane & 7) << 2);   // bank swizzle
                *reinterpret_cast<f32x4*>(&sm.r.y[qw][lane][jb]) = y[qf][df];
            }
#pragma unroll
        for (int qf = 0; qf < 4; ++qf) sm.r.l[qw][lane][qf] = l_[qf];
    }
    __syncthreads();
    if (kw == 0) {
#pragma unroll
        for (int qf = 0; qf < 4; ++qf) {
#pragma unroll
            for (int df = 0; df < 4; ++df) {
                const int jb = (qf * 16 + df * 4) ^ ((lane & 7) << 2);
                const f32x4 yp = *reinterpret_cast<const f32x4*>(&sm.r.y[qw][lane][jb]);
                y[qf][df] += yp;
            }
            float l = l_[qf] + sm.r.l[qw][lane][qf];
            l += __shfl_xor(l, 16);
            l += __shfl_xor(l, 32);
            const float rl = 1.f / l;
            half_t* Yp = Y + (size_t)(b * NT + q0 + qf * 16 + lr) * NC + h * ND + g * 4;
#pragma unroll
            for (int df = 0; df < 4; ++df) {
                union { f16x4 v; fp16x2 hh[2]; } o;
                o.hh[0] = __builtin_amdgcn_cvt_pkrtz(y[qf][df][0] * rl, y[qf][df][1] * rl);
                o.hh[1] = __builtin_amdgcn_cvt_pkrtz(y[qf][df][2] * rl, y[qf][df][3] * rl);
                *reinterpret_cast<f16x4*>(Yp + df * 16) = o.v;
            }
        }
    }
}

extern "C" void kernel_launch(void* const* d_in, const int* in_sizes, int n_in,
                              void* d_out, int out_size, void* d_ws, size_t ws_size,
                              hipStream_t stream) {
    const float* x  = (const float*)d_in[0];
    const float* Wa = (const float*)d_in[1];
    const float* ba = (const float*)d_in[2];
    const float* Wp = (const float*)d_in[3];
    const float* bp = (const float*)d_in[4];
    float* out = (float*)d_out;

    char* ws = (char*)d_ws;
    half_t* xh   = (half_t*)ws; ws += (size_t)NBT * NC * 2;
    half_t* Wat  = (half_t*)ws; ws += (size_t)NQKV * NC * 2;
    half_t* Wpt  = (half_t*)ws; ws += (size_t)NC * NC * 2;
    half_t* qkvh = (half_t*)ws; ws += (size_t)NBT * NQKV * 2;
    half_t* vt   = (half_t*)ws; ws += (size_t)NB * NH * ND * NT * 2;
    half_t* yh   = (half_t*)ws; ws += (size_t)NBT * NC * 2;

    k_prep<<<PREP_BLKS, 256, 0, stream>>>(x, xh, Wa, Wat, Wp, Wpt);
    k_gemm<0><<<dim3(NBT / 128, NQKV / 128), 256, 0, stream>>>(xh, Wat, ba, qkvh, NQKV, vt);
    k_attn<<<dim3(NT / 128, NB * NH), 256, 0, stream>>>(qkvh, vt, yh);
    k_gemm<1><<<dim3(NBT / 128, NC / 128), 256, 0, stream>>>(yh, Wpt, bp, out, NC, nullptr);
}

// Round 9
// 184.491 us; speedup vs baseline: 1.2253x; 1.0534x over previous
//
#include <hip/hip_runtime.h>
#include <stdint.h>

#define NB 2
#define NT 4096
#define NC 768
#define NH 12
#define ND 64
#define NBT (NB*NT)      // 8192
#define NQKV (3*NC)      // 2304

typedef _Float16 half_t;
typedef __attribute__((ext_vector_type(8))) _Float16 f16x8;
typedef __attribute__((ext_vector_type(4))) _Float16 f16x4;
typedef __attribute__((ext_vector_type(2))) __fp16 fp16x2;   // native type of cvt_pkrtz
typedef __attribute__((ext_vector_type(4))) float f32x4;

#define MFMA16(a,b,c) __builtin_amdgcn_mfma_f32_16x16x32_f16((a),(b),(c),0,0,0)

__device__ __forceinline__ void load_lds16(const void* g, void* l) {
    auto gp = reinterpret_cast<__attribute__((address_space(1))) char*>(reinterpret_cast<uintptr_t>(g));
    auto lp = reinterpret_cast<__attribute__((address_space(3))) char*>(reinterpret_cast<uintptr_t>(l));
    __builtin_amdgcn_global_load_lds(gp, lp, 16, 0, 0);
}

// ---------------- prep: fused {pack x fp32->f16} + {tiled transpose Wa} + {tiled transpose Wp} ----------------
#define PACK_BLKS ((NBT * NC / 4) / 256)          // 6144
#define WA_TILES ((NC / 32) * (NQKV / 32))        // 24*72 = 1728
#define WP_TILES ((NC / 32) * (NC / 32))          // 24*24 = 576
#define PREP_BLKS (PACK_BLKS + WA_TILES + WP_TILES)

__global__ __launch_bounds__(256) void k_prep(const float* __restrict__ x, half_t* __restrict__ xh,
                                              const float* __restrict__ Wa, half_t* __restrict__ Wat,
                                              const float* __restrict__ Wp, half_t* __restrict__ Wpt) {
    const int bid = blockIdx.x, tid = threadIdx.x;
    if (bid < PACK_BLKS) {
        const int i = bid * 256 + tid;
        float4 f = reinterpret_cast<const float4*>(x)[i];
        f16x4 h;
        h[0] = (half_t)f.x; h[1] = (half_t)f.y; h[2] = (half_t)f.z; h[3] = (half_t)f.w;
        reinterpret_cast<f16x4*>(xh)[i] = h;
        return;
    }
    __shared__ half_t tile[32][36];
    const float* in; half_t* out; int N, kt, nt;
    if (bid < PACK_BLKS + WA_TILES) {
        const int t = bid - PACK_BLKS;
        in = Wa; out = Wat; N = NQKV;
        kt = t / (NQKV / 32); nt = t - kt * (NQKV / 32);
    } else {
        const int t = bid - PACK_BLKS - WA_TILES;
        in = Wp; out = Wpt; N = NC;
        kt = t / (NC / 32); nt = t - kt * (NC / 32);
    }
    const int k0 = kt * 32, n0 = nt * 32;
    {
        const int r = tid >> 3, c = (tid & 7) * 4;
        float4 f = *reinterpret_cast<const float4*>(&in[(size_t)(k0 + r) * N + n0 + c]);
        tile[r][c] = (half_t)f.x; tile[r][c + 1] = (half_t)f.y;
        tile[r][c + 2] = (half_t)f.z; tile[r][c + 3] = (half_t)f.w;
    }
    __syncthreads();
    {
        const int rn = tid >> 3, ck = (tid & 7) * 4;
        f16x4 u;
        u[0] = tile[ck][rn]; u[1] = tile[ck + 1][rn];
        u[2] = tile[ck + 2][rn]; u[3] = tile[ck + 3][rn];
        *reinterpret_cast<f16x4*>(&out[(size_t)(n0 + rn) * NC + k0 + ck]) = u;
    }
}

// ---------------- GEMM0: qkv = xh * Wat^T + ba. 128x192 tile -> grid 64x12 = 768 blocks ----------------
// R8: the old 128^2 grid was 1152 blocks at 3/CU = 768 slots -> 1.5 dispatch rounds ->
// ~75% CU utilization (~10us of pure quantization loss). 2304 = 192*12, so a 128x192
// tile gives exactly 768 blocks = 3/CU, all resident, perfectly balanced. Wave tile
// 64x96: 4 af + 6 bf LDS reads feed 24 MFMA (reads/MFMA 0.5 -> 0.42), barriers/FLOP
// 1.5x fewer. LDS 40KB -> 3 blocks/CU. bf read in-loop keeps VGPR ~150 < 170 cap of
// (256,3). V n-tiles (by>=8, n0>=1536=8*192) skip qkvh and write Vt[bh][d][t] via a
// wave-private 8KB LDS transpose in two 48-col passes (wave-local: no barrier needed
// after the K-loop's final syncthreads; same XOR swizzle family as R7).
__global__ __launch_bounds__(256, 3) void k_gemm0(const half_t* __restrict__ A, const half_t* __restrict__ Bt,
                                                  const float* __restrict__ bias, half_t* __restrict__ out,
                                                  half_t* __restrict__ Vt) {
    __shared__ half_t As[2][128 * 32];
    __shared__ half_t Bs[2][192 * 32];
    const int tid = threadIdx.x;
    const int lane = tid & 63, w = tid >> 6;
    const int m0 = blockIdx.x * 128, n0 = blockIdx.y * 192;
    const int wm = (w >> 1) * 64, wn = (w & 1) * 96;
    const int lr = lane & 15, lk = (lane >> 4) * 8;

    f32x4 acc[4][6];
#pragma unroll
    for (int a = 0; a < 4; ++a)
#pragma unroll
        for (int bq = 0; bq < 6; ++bq) acc[a][bq] = (f32x4){0.f, 0.f, 0.f, 0.f};

    const int ldsbase = (tid & ~63) * 16;   // wave-uniform byte base for global_load_lds
    const half_t* Arow = A  + (size_t)(m0 + (tid >> 2)) * NC + (tid & 3) * 8;
    const half_t* Brow = Bt + (size_t)(n0 + (tid >> 2)) * NC + (tid & 3) * 8;

    auto stage = [&](int buf, int k0) {
        load_lds16(Arow + k0,                    (char*)&As[buf][0] + ldsbase);
        load_lds16(Arow + (size_t)64 * NC + k0,  (char*)&As[buf][0] + 4096 + ldsbase);
        load_lds16(Brow + k0,                    (char*)&Bs[buf][0] + ldsbase);
        load_lds16(Brow + (size_t)64 * NC + k0,  (char*)&Bs[buf][0] + 4096 + ldsbase);
        load_lds16(Brow + (size_t)128 * NC + k0, (char*)&Bs[buf][0] + 8192 + ldsbase);
    };

    stage(0, 0);
    __syncthreads();
    int cur = 0;

    for (int ks = 0; ks < 24; ++ks) {
        if (ks < 23) stage(cur ^ 1, (ks + 1) * 32);
        f16x8 af[4];
#pragma unroll
        for (int mi = 0; mi < 4; ++mi)
            af[mi] = *reinterpret_cast<const f16x8*>(&As[cur][(wm + mi * 16 + lr) * 32 + lk]);
#pragma unroll
        for (int ni = 0; ni < 6; ++ni) {
            f16x8 bf = *reinterpret_cast<const f16x8*>(&Bs[cur][(wn + ni * 16 + lr) * 32 + lk]);
#pragma unroll
            for (int mi = 0; mi < 4; ++mi)
                acc[mi][ni] = MFMA16(af[mi], bf, acc[mi][ni]);
        }
        __syncthreads();   // drains stage vmcnt (overlapped by compute) + fences buf reads
        cur ^= 1;
    }

    const int rg = (lane >> 4) * 4;   // C/D layout: row=(lane>>4)*4+i, col=lane&15

    if (n0 >= 2 * NC) {
        // ---- V epilogue: two 48-col passes, wave-private 8KB LDS scratch ----
        half_t* q = (w < 2) ? (half_t*)((char*)&As[0][0] + w * 8192)
                            : (half_t*)((char*)&Bs[0][0] + (w - 2) * 8192);
        const int M0 = m0 + wm;
        const int bb = M0 >> 12;
        const int trow = M0 & (NT - 1);
#pragma unroll
        for (int p = 0; p < 2; ++p) {
#pragma unroll
            for (int n3 = 0; n3 < 3; ++n3) {
                const int ni = p * 3 + n3;
                const int c = n3 * 16 + lr;                  // local col 0..47
                const float bv = bias[n0 + wn + p * 48 + c];
                const int xsw = (c & 7) << 3;
#pragma unroll
                for (int mi = 0; mi < 4; ++mi) {
                    const int t0 = mi * 16 + rg;             // 4-aligned, XOR bits 3-5 only
                    union { f16x4 v; fp16x2 hh[2]; } o;
                    o.hh[0] = __builtin_amdgcn_cvt_pkrtz(acc[mi][ni][0] + bv, acc[mi][ni][1] + bv);
                    o.hh[1] = __builtin_amdgcn_cvt_pkrtz(acc[mi][ni][2] + bv, acc[mi][ni][3] + bv);
                    *reinterpret_cast<f16x4*>(&q[c * 64 + (t0 ^ xsw)]) = o.v;
                }
            }
            // wave-local read-back (same-wave DS ops are in-order; no block barrier)
#pragma unroll
            for (int j = 0; j < 6; ++j) {
                const int cl = j * 8 + (lane >> 3);          // local col 0..47
                const int tt = (lane & 7) * 8;               // 8-aligned
                f16x8 val = *reinterpret_cast<const f16x8*>(&q[cl * 64 + (tt ^ ((cl & 7) << 3))]);
                const int dcol = n0 - 2 * NC + wn + p * 48 + cl;   // 0..767
                const int bh = bb * NH + (dcol >> 6);
                *reinterpret_cast<f16x8*>(&Vt[((size_t)bh * ND + (dcol & 63)) * NT + trow + tt]) = val;
            }
        }
        return;
    }

    // ---- QK epilogue: f16 to qkvh (row stride NQKV) ----
#pragma unroll
    for (int ni = 0; ni < 6; ++ni) {
        const int gn = n0 + wn + ni * 16 + lr;
        const float bv = bias[gn];
#pragma unroll
        for (int mi = 0; mi < 4; ++mi)
#pragma unroll
            for (int i = 0; i < 4; ++i) {
                const size_t gm = (size_t)(m0 + wm + mi * 16 + rg + i);
                out[gm * NQKV + gn] = (half_t)(acc[mi][ni][i] + bv);
            }
    }
}

// ---------------- GEMM1: out = yh * Wpt^T + bp (128^2, f32 out; 384 blocks all-resident) ----------------
__global__ __launch_bounds__(256) void k_gemm(const half_t* __restrict__ A, const half_t* __restrict__ Bt,
                                              const float* __restrict__ bias, float* __restrict__ out, int N) {
    __shared__ half_t As[2][128 * 32];
    __shared__ half_t Bs[2][128 * 32];
    const int tid = threadIdx.x;
    const int lane = tid & 63, w = tid >> 6;
    const int m0 = blockIdx.x * 128, n0 = blockIdx.y * 128;
    const int wm = (w >> 1) * 64, wn = (w & 1) * 64;
    const int lr = lane & 15, lk = (lane >> 4) * 8;

    f32x4 acc[4][4];
#pragma unroll
    for (int a = 0; a < 4; ++a)
#pragma unroll
        for (int bq = 0; bq < 4; ++bq) acc[a][bq] = (f32x4){0.f, 0.f, 0.f, 0.f};

    const int c0 = tid, c1 = 256 + tid;
    const int ldsbase = (tid & ~63) * 16;   // wave-uniform byte base for global_load_lds
    const half_t* A0 = A  + (size_t)(m0 + (c0 >> 2)) * NC + (c0 & 3) * 8;
    const half_t* A1 = A  + (size_t)(m0 + (c1 >> 2)) * NC + (c1 & 3) * 8;
    const half_t* B0 = Bt + (size_t)(n0 + (c0 >> 2)) * NC + (c0 & 3) * 8;
    const half_t* B1 = Bt + (size_t)(n0 + (c1 >> 2)) * NC + (c1 & 3) * 8;

    auto stage = [&](int buf, int k0) {
        load_lds16(A0 + k0, (char*)&As[buf][0] + ldsbase);
        load_lds16(B0 + k0, (char*)&Bs[buf][0] + ldsbase);
        load_lds16(A1 + k0, (char*)&As[buf][0] + 4096 + ldsbase);
        load_lds16(B1 + k0, (char*)&Bs[buf][0] + 4096 + ldsbase);
    };

    stage(0, 0);
    __syncthreads();
    int cur = 0;

    for (int ks = 0; ks < 24; ++ks) {
        if (ks < 23) stage(cur ^ 1, (ks + 1) * 32);
        f16x8 af[4], bf[4];
#pragma unroll
        for (int mi = 0; mi < 4; ++mi)
            af[mi] = *reinterpret_cast<const f16x8*>(&As[cur][(wm + mi * 16 + lr) * 32 + lk]);
#pragma unroll
        for (int ni = 0; ni < 4; ++ni)
            bf[ni] = *reinterpret_cast<const f16x8*>(&Bs[cur][(wn + ni * 16 + lr) * 32 + lk]);
#pragma unroll
        for (int mi = 0; mi < 4; ++mi)
#pragma unroll
            for (int ni = 0; ni < 4; ++ni)
                acc[mi][ni] = MFMA16(af[mi], bf[ni], acc[mi][ni]);
        __syncthreads();
        cur ^= 1;
    }

    const int rg = (lane >> 4) * 4;   // C/D layout: row=(lane>>4)*4+i, col=lane&15
#pragma unroll
    for (int ni = 0; ni < 4; ++ni) {
        const int gn = n0 + wn + ni * 16 + lr;
        const float bv = bias[gn];
#pragma unroll
        for (int mi = 0; mi < 4; ++mi)
#pragma unroll
            for (int i = 0; i < 4; ++i) {
                const size_t gm = (size_t)(m0 + wm + mi * 16 + rg + i);
                out[gm * N + gn] = acc[mi][ni][i] + bv;
            }
    }
}

// ---------------- Flash attention v9: q=64/wave AND 12 waves/CU (qw x kw wave grid) ----------------
// Ledger: R0 8w-split regressed (too little work/wave/barrier); R1 counted-vmcnt neutral;
// R2 score-lookahead spilled (FETCH 10x); R3 q=64 @ 6 waves/CU: conflicts halved but
// latency-exposed; R4 = q=64 + 12 waves/CU: WIN 133->119us. R5 per-qf softmax/PV fusion
// REGRESSED (broke phase-level ILP). Structure frozen at v9.
struct __align__(16) AttnSmem {
    union {
        struct { half_t K[2][64 * 64]; half_t V[2][64 * 64]; } m;   // 32 KB main
        struct { float y[2][64][64]; float l[2][64][4]; } r;        // 34 KB epilogue
    };
};

__global__ __launch_bounds__(256, 3) void k_attn(const half_t* __restrict__ qkv, const half_t* __restrict__ Vt,
                                                 half_t* __restrict__ Y) {
    __shared__ AttnSmem sm;
    const int tid = threadIdx.x, lane = tid & 63, w = tid >> 6;
    const int qw = w & 1, kw = w >> 1;
    const int lr = lane & 15, g = lane >> 4;
    const int qt = blockIdx.x, bh = blockIdx.y;
    const int b = bh / NH, h = bh - b * NH;
    const half_t* Qp = qkv + (size_t)b * NT * NQKV + h * ND;        // q cols
    const half_t* Kp = Qp + NC;                                     // k cols
    const half_t* Vbase = Vt + (size_t)bh * ND * NT;                // V^T [d][t]
    const int q0 = qt * 128 + qw * 64;

    // staging geometry: 256 threads x 16B = 4KB per instr = 32 rows of 128B; 2 instrs per 8KB tile
    const int sr = tid >> 3;                                   // row 0..31 (instr0), +32 (instr1)
    const int colh = (((tid & 7) << 3)) ^ ((sr & 7) << 3);     // swizzled source col (halfs)
    const int wub = (tid & ~63) * 16;                          // wave-uniform LDS byte base

    // Q fragments (B-operand: col=lr=q), 4 q-frags x 2 d-halves, pre-scaled by 1/sqrt(D)*log2(e)
    f16x8 aq[4][2];
    const half_t cch = (half_t)(0.125f * 1.4426950408889634f);
#pragma unroll
    for (int qf = 0; qf < 4; ++qf)
#pragma unroll
        for (int dh = 0; dh < 2; ++dh) {
            aq[qf][dh] = *reinterpret_cast<const f16x8*>(&Qp[(size_t)(q0 + qf * 16 + lr) * NQKV + dh * 32 + g * 8]);
#pragma unroll
            for (int j = 0; j < 8; ++j) aq[qf][dh][j] = aq[qf][dh][j] * cch;
        }

    // swizzled K-read columns (b128): row = st*16+lr, chunk ^= (lr&7)
    const int swk = (lr & 7) << 3;
    const int cA = (g * 8) ^ swk;          // d-chunk 0
    const int cB = (32 + g * 8) ^ swk;     // d-chunk 1
    // swizzled V-read columns (b64 pairs) for this wave's key-half (ks = kw)
    const int psw = lr & 7;
    const int goff = (g & 1) << 2;
    const int vcol[2] = { (((g >> 1) + 4 * kw + 0) ^ psw) * 8 + goff,
                          (((g >> 1) + 4 * kw + 2) ^ psw) * 8 + goff };

    f32x4 y[4][4];
#pragma unroll
    for (int qf = 0; qf < 4; ++qf)
#pragma unroll
        for (int df = 0; df < 4; ++df) y[qf][df] = (f32x4){0.f, 0.f, 0.f, 0.f};
    float l_[4] = {0.f, 0.f, 0.f, 0.f};

    auto stagebuf = [&](int buf, const half_t* Ks, const half_t* Vs) {
        char* kdst = (char*)&sm.m.K[buf][0] + wub;
        char* vdst = (char*)&sm.m.V[buf][0] + wub;
        load_lds16(Ks, kdst);
        load_lds16(Ks + (size_t)32 * NQKV, kdst + 4096);
        load_lds16(Vs, vdst);
        load_lds16(Vs + (size_t)32 * NT, vdst + 4096);
    };

    const half_t* ksrc = Kp + (size_t)sr * NQKV + colh;
    const half_t* vsrc = Vbase + (size_t)sr * NT + colh;
    stagebuf(0, ksrc, vsrc);
    ksrc += (size_t)64 * NQKV;
    vsrc += 64;
    __syncthreads();
    int cur = 0;
    const int stb = 2 * kw;

    for (int t = 0; t < NT / 64; ++t) {
        if (t < NT / 64 - 1) {
            stagebuf(cur ^ 1, ksrc, vsrc);
            ksrc += (size_t)64 * NQKV;
            vsrc += 64;
        }

        // ---- QK^T (swapped), this wave's 32-key half: s[qf][sl][i], st = stb+sl ----
        f32x4 s[4][2];
#pragma unroll
        for (int qf = 0; qf < 4; ++qf) { s[qf][0] = (f32x4){0.f,0.f,0.f,0.f}; s[qf][1] = (f32x4){0.f,0.f,0.f,0.f}; }
        const half_t* Kc = &sm.m.K[cur][0];
        __builtin_amdgcn_s_setprio(1);
#pragma unroll
        for (int sl = 0; sl < 2; ++sl) {
            const int row = (stb + sl) * 16 + lr;
            f16x8 bk0 = *reinterpret_cast<const f16x8*>(&Kc[row * 64 + cA]);
            s[0][sl] = MFMA16(bk0, aq[0][0], s[0][sl]);
            s[1][sl] = MFMA16(bk0, aq[1][0], s[1][sl]);
            s[2][sl] = MFMA16(bk0, aq[2][0], s[2][sl]);
            s[3][sl] = MFMA16(bk0, aq[3][0], s[3][sl]);
            f16x8 bk1 = *reinterpret_cast<const f16x8*>(&Kc[row * 64 + cB]);
            s[0][sl] = MFMA16(bk1, aq[0][1], s[0][sl]);
            s[1][sl] = MFMA16(bk1, aq[1][1], s[1][sl]);
            s[2][sl] = MFMA16(bk1, aq[2][1], s[2][sl]);
            s[3][sl] = MFMA16(bk1, aq[3][1], s[3][sl]);
        }
        __builtin_amdgcn_s_setprio(0);

        // ---- no-max softmax + lane-local pack: pb[qf] = packed p for this key-half ----
        f16x8 pb[4];
#pragma unroll
        for (int qf = 0; qf < 4; ++qf) {
            float ps = 0.f;
            union { f16x8 v; fp16x2 h[4]; } u;
#pragma unroll
            for (int hs = 0; hs < 2; ++hs) {   // hs: local st within this ks
                const float p0 = __builtin_amdgcn_exp2f(s[qf][hs][0]);
                const float p1 = __builtin_amdgcn_exp2f(s[qf][hs][1]);
                const float p2 = __builtin_amdgcn_exp2f(s[qf][hs][2]);
                const float p3 = __builtin_amdgcn_exp2f(s[qf][hs][3]);
                u.h[2 * hs]     = __builtin_amdgcn_cvt_pkrtz(p0, p1);
                u.h[2 * hs + 1] = __builtin_amdgcn_cvt_pkrtz(p2, p3);
                ps += (p0 + p1) + (p2 + p3);
            }
            pb[qf] = u.v;
            l_[qf] += ps;
        }

        // ---- PV (ks = kw): A = V^T rows, B = pb (register) ----
        const half_t* Vc = &sm.m.V[cur][0];
        __builtin_amdgcn_s_setprio(1);
#pragma unroll
        for (int df = 0; df < 4; ++df) {
            const half_t* vrow = &Vc[(df * 16 + lr) * 64];
            union { f16x8 v; f16x4 q[2]; } va;
            va.q[0] = *reinterpret_cast<const f16x4*>(vrow + vcol[0]);
            va.q[1] = *reinterpret_cast<const f16x4*>(vrow + vcol[1]);
            y[0][df] = MFMA16(va.v, pb[0], y[0][df]);
            y[1][df] = MFMA16(va.v, pb[1], y[1][df]);
            y[2][df] = MFMA16(va.v, pb[2], y[2][df]);
            y[3][df] = MFMA16(va.v, pb[3], y[3][df]);
        }
        __builtin_amdgcn_s_setprio(0);

        __syncthreads();   // drains stage vmcnt + all waves done reading buf[cur]
        cur ^= 1;
    }

    // ---- cross-wave (key-half) reduction: kw=1 publishes y/l, kw=0 combines+stores ----
    if (kw == 1) {
#pragma unroll
        for (int qf = 0; qf < 4; ++qf)
#pragma unroll
            for (int df = 0; df < 4; ++df) {
                const int jb = (qf * 16 + df * 4) ^ ((lane & 7) << 2);   // bank swizzle
                *reinterpret_cast<f32x4*>(&sm.r.y[qw][lane][jb]) = y[qf][df];
            }
#pragma unroll
        for (int qf = 0; qf < 4; ++qf) sm.r.l[qw][lane][qf] = l_[qf];
    }
    __syncthreads();
    if (kw == 0) {
#pragma unroll
        for (int qf = 0; qf < 4; ++qf) {
#pragma unroll
            for (int df = 0; df < 4; ++df) {
                const int jb = (qf * 16 + df * 4) ^ ((lane & 7) << 2);
                const f32x4 yp = *reinterpret_cast<const f32x4*>(&sm.r.y[qw][lane][jb]);
                y[qf][df] += yp;
            }
            float l = l_[qf] + sm.r.l[qw][lane][qf];
            l += __shfl_xor(l, 16);
            l += __shfl_xor(l, 32);
            const float rl = 1.f / l;
            half_t* Yp = Y + (size_t)(b * NT + q0 + qf * 16 + lr) * NC + h * ND + g * 4;
#pragma unroll
            for (int df = 0; df < 4; ++df) {
                union { f16x4 v; fp16x2 hh[2]; } o;
                o.hh[0] = __builtin_amdgcn_cvt_pkrtz(y[qf][df][0] * rl, y[qf][df][1] * rl);
                o.hh[1] = __builtin_amdgcn_cvt_pkrtz(y[qf][df][2] * rl, y[qf][df][3] * rl);
                *reinterpret_cast<f16x4*>(Yp + df * 16) = o.v;
            }
        }
    }
}

extern "C" void kernel_launch(void* const* d_in, const int* in_sizes, int n_in,
                              void* d_out, int out_size, void* d_ws, size_t ws_size,
                              hipStream_t stream) {
    const float* x  = (const float*)d_in[0];
    const float* Wa = (const float*)d_in[1];
    const float* ba = (const float*)d_in[2];
    const float* Wp = (const float*)d_in[3];
    const float* bp = (const float*)d_in[4];
    float* out = (float*)d_out;

    char* ws = (char*)d_ws;
    half_t* xh   = (half_t*)ws; ws += (size_t)NBT * NC * 2;
    half_t* Wat  = (half_t*)ws; ws += (size_t)NQKV * NC * 2;
    half_t* Wpt  = (half_t*)ws; ws += (size_t)NC * NC * 2;
    half_t* qkvh = (half_t*)ws; ws += (size_t)NBT * NQKV * 2;
    half_t* vt   = (half_t*)ws; ws += (size_t)NB * NH * ND * NT * 2;
    half_t* yh   = (half_t*)ws; ws += (size_t)NBT * NC * 2;

    k_prep<<<PREP_BLKS, 256, 0, stream>>>(x, xh, Wa, Wat, Wp, Wpt);
    k_gemm0<<<dim3(NBT / 128, NQKV / 192), 256, 0, stream>>>(xh, Wat, ba, qkvh, vt);
    k_attn<<<dim3(NT / 128, NB * NH), 256, 0, stream>>>(qkvh, vt, yh);
    k_gemm<<<dim3(NBT / 128, NC / 128), 256, 0, stream>>>(yh, Wpt, bp, out, NC);
}

// Round 10
// 183.742 us; speedup vs baseline: 1.2303x; 1.0041x over previous
//
#include <hip/hip_runtime.h>
#include <stdint.h>

#define NB 2
#define NT 4096
#define NC 768
#define NH 12
#define ND 64
#define NBT (NB*NT)      // 8192
#define NQKV (3*NC)      // 2304

typedef _Float16 half_t;
typedef __attribute__((ext_vector_type(8))) _Float16 f16x8;
typedef __attribute__((ext_vector_type(4))) _Float16 f16x4;
typedef __attribute__((ext_vector_type(2))) __fp16 fp16x2;   // native type of cvt_pkrtz
typedef __attribute__((ext_vector_type(4))) float f32x4;

#define MFMA16(a,b,c) __builtin_amdgcn_mfma_f32_16x16x32_f16((a),(b),(c),0,0,0)

__device__ __forceinline__ void load_lds16(const void* g, void* l) {
    auto gp = reinterpret_cast<__attribute__((address_space(1))) char*>(reinterpret_cast<uintptr_t>(g));
    auto lp = reinterpret_cast<__attribute__((address_space(3))) char*>(reinterpret_cast<uintptr_t>(l));
    __builtin_amdgcn_global_load_lds(gp, lp, 16, 0, 0);
}

// ---------------- prep: fused {pack x fp32->f16} + {tiled transpose Wa} + {tiled transpose Wp} ----------------
#define PACK_BLKS ((NBT * NC / 4) / 256)          // 6144
#define WA_TILES ((NC / 32) * (NQKV / 32))        // 24*72 = 1728
#define WP_TILES ((NC / 32) * (NC / 32))          // 24*24 = 576
#define PREP_BLKS (PACK_BLKS + WA_TILES + WP_TILES)

__global__ __launch_bounds__(256) void k_prep(const float* __restrict__ x, half_t* __restrict__ xh,
                                              const float* __restrict__ Wa, half_t* __restrict__ Wat,
                                              const float* __restrict__ Wp, half_t* __restrict__ Wpt) {
    const int bid = blockIdx.x, tid = threadIdx.x;
    if (bid < PACK_BLKS) {
        const int i = bid * 256 + tid;
        float4 f = reinterpret_cast<const float4*>(x)[i];
        f16x4 h;
        h[0] = (half_t)f.x; h[1] = (half_t)f.y; h[2] = (half_t)f.z; h[3] = (half_t)f.w;
        reinterpret_cast<f16x4*>(xh)[i] = h;
        return;
    }
    __shared__ half_t tile[32][36];
    const float* in; half_t* out; int N, kt, nt;
    if (bid < PACK_BLKS + WA_TILES) {
        const int t = bid - PACK_BLKS;
        in = Wa; out = Wat; N = NQKV;
        kt = t / (NQKV / 32); nt = t - kt * (NQKV / 32);
    } else {
        const int t = bid - PACK_BLKS - WA_TILES;
        in = Wp; out = Wpt; N = NC;
        kt = t / (NC / 32); nt = t - kt * (NC / 32);
    }
    const int k0 = kt * 32, n0 = nt * 32;
    {
        const int r = tid >> 3, c = (tid & 7) * 4;
        float4 f = *reinterpret_cast<const float4*>(&in[(size_t)(k0 + r) * N + n0 + c]);
        tile[r][c] = (half_t)f.x; tile[r][c + 1] = (half_t)f.y;
        tile[r][c + 2] = (half_t)f.z; tile[r][c + 3] = (half_t)f.w;
    }
    __syncthreads();
    {
        const int rn = tid >> 3, ck = (tid & 7) * 4;
        f16x4 u;
        u[0] = tile[ck][rn]; u[1] = tile[ck + 1][rn];
        u[2] = tile[ck + 2][rn]; u[3] = tile[ck + 3][rn];
        *reinterpret_cast<f16x4*>(&out[(size_t)(n0 + rn) * NC + k0 + ck]) = u;
    }
}

// ---------------- GEMM0: qkv = xh * Wat^T + ba. 128x192 tile -> grid 64x12 = 768 blocks ----------------
// R8 WIN: grid 768 = exactly 3/CU, balanced (was 1152 -> 1.5 dispatch rounds).
// V n-tiles (n0 >= 1536 = 8*192) skip qkvh and write Vt[bh][d][t] via wave-private 8KB
// LDS transpose in two 48-col passes (wave-local; same XOR swizzle family as R7).
__global__ __launch_bounds__(256, 3) void k_gemm0(const half_t* __restrict__ A, const half_t* __restrict__ Bt,
                                                  const float* __restrict__ bias, half_t* __restrict__ out,
                                                  half_t* __restrict__ Vt) {
    __shared__ half_t As[2][128 * 32];
    __shared__ half_t Bs[2][192 * 32];
    const int tid = threadIdx.x;
    const int lane = tid & 63, w = tid >> 6;
    const int m0 = blockIdx.x * 128, n0 = blockIdx.y * 192;
    const int wm = (w >> 1) * 64, wn = (w & 1) * 96;
    const int lr = lane & 15, lk = (lane >> 4) * 8;

    f32x4 acc[4][6];
#pragma unroll
    for (int a = 0; a < 4; ++a)
#pragma unroll
        for (int bq = 0; bq < 6; ++bq) acc[a][bq] = (f32x4){0.f, 0.f, 0.f, 0.f};

    const int ldsbase = (tid & ~63) * 16;   // wave-uniform byte base for global_load_lds
    const half_t* Arow = A  + (size_t)(m0 + (tid >> 2)) * NC + (tid & 3) * 8;
    const half_t* Brow = Bt + (size_t)(n0 + (tid >> 2)) * NC + (tid & 3) * 8;

    auto stage = [&](int buf, int k0) {
        load_lds16(Arow + k0,                    (char*)&As[buf][0] + ldsbase);
        load_lds16(Arow + (size_t)64 * NC + k0,  (char*)&As[buf][0] + 4096 + ldsbase);
        load_lds16(Brow + k0,                    (char*)&Bs[buf][0] + ldsbase);
        load_lds16(Brow + (size_t)64 * NC + k0,  (char*)&Bs[buf][0] + 4096 + ldsbase);
        load_lds16(Brow + (size_t)128 * NC + k0, (char*)&Bs[buf][0] + 8192 + ldsbase);
    };

    stage(0, 0);
    __syncthreads();
    int cur = 0;

    for (int ks = 0; ks < 24; ++ks) {
        if (ks < 23) stage(cur ^ 1, (ks + 1) * 32);
        f16x8 af[4];
#pragma unroll
        for (int mi = 0; mi < 4; ++mi)
            af[mi] = *reinterpret_cast<const f16x8*>(&As[cur][(wm + mi * 16 + lr) * 32 + lk]);
#pragma unroll
        for (int ni = 0; ni < 6; ++ni) {
            f16x8 bf = *reinterpret_cast<const f16x8*>(&Bs[cur][(wn + ni * 16 + lr) * 32 + lk]);
#pragma unroll
            for (int mi = 0; mi < 4; ++mi)
                acc[mi][ni] = MFMA16(af[mi], bf, acc[mi][ni]);
        }
        __syncthreads();   // drains stage vmcnt (overlapped by compute) + fences buf reads
        cur ^= 1;
    }

    const int rg = (lane >> 4) * 4;   // C/D layout: row=(lane>>4)*4+i, col=lane&15

    if (n0 >= 2 * NC) {
        // ---- V epilogue: two 48-col passes, wave-private 8KB LDS scratch ----
        half_t* q = (w < 2) ? (half_t*)((char*)&As[0][0] + w * 8192)
                            : (half_t*)((char*)&Bs[0][0] + (w - 2) * 8192);
        const int M0 = m0 + wm;
        const int bb = M0 >> 12;
        const int trow = M0 & (NT - 1);
#pragma unroll
        for (int p = 0; p < 2; ++p) {
#pragma unroll
            for (int n3 = 0; n3 < 3; ++n3) {
                const int ni = p * 3 + n3;
                const int c = n3 * 16 + lr;                  // local col 0..47
                const float bv = bias[n0 + wn + p * 48 + c];
                const int xsw = (c & 7) << 3;
#pragma unroll
                for (int mi = 0; mi < 4; ++mi) {
                    const int t0 = mi * 16 + rg;             // 4-aligned, XOR bits 3-5 only
                    union { f16x4 v; fp16x2 hh[2]; } o;
                    o.hh[0] = __builtin_amdgcn_cvt_pkrtz(acc[mi][ni][0] + bv, acc[mi][ni][1] + bv);
                    o.hh[1] = __builtin_amdgcn_cvt_pkrtz(acc[mi][ni][2] + bv, acc[mi][ni][3] + bv);
                    *reinterpret_cast<f16x4*>(&q[c * 64 + (t0 ^ xsw)]) = o.v;
                }
            }
            // wave-local read-back (same-wave DS ops are in-order; no block barrier)
#pragma unroll
            for (int j = 0; j < 6; ++j) {
                const int cl = j * 8 + (lane >> 3);          // local col 0..47
                const int tt = (lane & 7) * 8;               // 8-aligned
                f16x8 val = *reinterpret_cast<const f16x8*>(&q[cl * 64 + (tt ^ ((cl & 7) << 3))]);
                const int dcol = n0 - 2 * NC + wn + p * 48 + cl;   // 0..767
                const int bh = bb * NH + (dcol >> 6);
                *reinterpret_cast<f16x8*>(&Vt[((size_t)bh * ND + (dcol & 63)) * NT + trow + tt]) = val;
            }
        }
        return;
    }

    // ---- QK epilogue: f16 to qkvh (row stride NQKV) ----
#pragma unroll
    for (int ni = 0; ni < 6; ++ni) {
        const int gn = n0 + wn + ni * 16 + lr;
        const float bv = bias[gn];
#pragma unroll
        for (int mi = 0; mi < 4; ++mi)
#pragma unroll
            for (int i = 0; i < 4; ++i) {
                const size_t gm = (size_t)(m0 + wm + mi * 16 + rg + i);
                out[gm * NQKV + gn] = (half_t)(acc[mi][ni][i] + bv);
            }
    }
}

// ---------------- GEMM1: out = yh * Wpt^T + bp. 128x96 tile -> grid 64x8 = 512 blocks = 2/CU ----------------
// R9: old 128^2 grid was 64x6 = 384 blocks on 256 CUs -> half the CUs ran 2 blocks, half
// ran 1 -> time = 2 full 128^2 block-rounds. 768 = 96*8, so 128x96 gives 512 blocks =
// exactly 2/CU balanced; max per-CU work drops 25%. Bs padded to 128 rows so staging
// stays two full 4KB global_load_lds; overrun rows (96..127 of last n-tile) land in
// adjacent allocated workspace (qkvh) and are never read by MFMA.
__global__ __launch_bounds__(256) void k_gemm1(const half_t* __restrict__ A, const half_t* __restrict__ Bt,
                                               const float* __restrict__ bias, float* __restrict__ out) {
    __shared__ half_t As[2][128 * 32];
    __shared__ half_t Bs[2][128 * 32];   // rows 96..127 = staging overrun pad
    const int tid = threadIdx.x;
    const int lane = tid & 63, w = tid >> 6;
    const int m0 = blockIdx.x * 128, n0 = blockIdx.y * 96;
    const int wm = (w >> 1) * 64, wn = (w & 1) * 48;
    const int lr = lane & 15, lk = (lane >> 4) * 8;

    f32x4 acc[4][3];
#pragma unroll
    for (int a = 0; a < 4; ++a)
#pragma unroll
        for (int bq = 0; bq < 3; ++bq) acc[a][bq] = (f32x4){0.f, 0.f, 0.f, 0.f};

    const int ldsbase = (tid & ~63) * 16;   // wave-uniform byte base for global_load_lds
    const half_t* Arow = A  + (size_t)(m0 + (tid >> 2)) * NC + (tid & 3) * 8;
    const half_t* Brow = Bt + (size_t)(n0 + (tid >> 2)) * NC + (tid & 3) * 8;

    auto stage = [&](int buf, int k0) {
        load_lds16(Arow + k0,                   (char*)&As[buf][0] + ldsbase);
        load_lds16(Arow + (size_t)64 * NC + k0, (char*)&As[buf][0] + 4096 + ldsbase);
        load_lds16(Brow + k0,                   (char*)&Bs[buf][0] + ldsbase);
        load_lds16(Brow + (size_t)64 * NC + k0, (char*)&Bs[buf][0] + 4096 + ldsbase);
    };

    stage(0, 0);
    __syncthreads();
    int cur = 0;

    for (int ks = 0; ks < 24; ++ks) {
        if (ks < 23) stage(cur ^ 1, (ks + 1) * 32);
        f16x8 af[4], bf[3];
#pragma unroll
        for (int mi = 0; mi < 4; ++mi)
            af[mi] = *reinterpret_cast<const f16x8*>(&As[cur][(wm + mi * 16 + lr) * 32 + lk]);
#pragma unroll
        for (int ni = 0; ni < 3; ++ni)
            bf[ni] = *reinterpret_cast<const f16x8*>(&Bs[cur][(wn + ni * 16 + lr) * 32 + lk]);
#pragma unroll
        for (int mi = 0; mi < 4; ++mi)
#pragma unroll
            for (int ni = 0; ni < 3; ++ni)
                acc[mi][ni] = MFMA16(af[mi], bf[ni], acc[mi][ni]);
        __syncthreads();
        cur ^= 1;
    }

    const int rg = (lane >> 4) * 4;   // C/D layout: row=(lane>>4)*4+i, col=lane&15
#pragma unroll
    for (int ni = 0; ni < 3; ++ni) {
        const int gn = n0 + wn + ni * 16 + lr;
        const float bv = bias[gn];
#pragma unroll
        for (int mi = 0; mi < 4; ++mi)
#pragma unroll
            for (int i = 0; i < 4; ++i) {
                const size_t gm = (size_t)(m0 + wm + mi * 16 + rg + i);
                out[gm * NC + gn] = acc[mi][ni][i] + bv;
            }
    }
}

// ---------------- Flash attention v9: q=64/wave AND 12 waves/CU (qw x kw wave grid) ----------------
// Ledger: R0 8w-split regressed (too little work/wave/barrier); R1 counted-vmcnt neutral;
// R2 score-lookahead spilled (FETCH 10x); R3 q=64 @ 6 waves/CU: conflicts halved but
// latency-exposed; R4 = q=64 + 12 waves/CU: WIN 133->119us. R5 per-qf softmax/PV fusion
// REGRESSED (broke phase-level ILP). Structure frozen at v9.
struct __align__(16) AttnSmem {
    union {
        struct { half_t K[2][64 * 64]; half_t V[2][64 * 64]; } m;   // 32 KB main
        struct { float y[2][64][64]; float l[2][64][4]; } r;        // 34 KB epilogue
    };
};

__global__ __launch_bounds__(256, 3) void k_attn(const half_t* __restrict__ qkv, const half_t* __restrict__ Vt,
                                                 half_t* __restrict__ Y) {
    __shared__ AttnSmem sm;
    const int tid = threadIdx.x, lane = tid & 63, w = tid >> 6;
    const int qw = w & 1, kw = w >> 1;
    const int lr = lane & 15, g = lane >> 4;
    const int qt = blockIdx.x, bh = blockIdx.y;
    const int b = bh / NH, h = bh - b * NH;
    const half_t* Qp = qkv + (size_t)b * NT * NQKV + h * ND;        // q cols
    const half_t* Kp = Qp + NC;                                     // k cols
    const half_t* Vbase = Vt + (size_t)bh * ND * NT;                // V^T [d][t]
    const int q0 = qt * 128 + qw * 64;

    // staging geometry: 256 threads x 16B = 4KB per instr = 32 rows of 128B; 2 instrs per 8KB tile
    const int sr = tid >> 3;                                   // row 0..31 (instr0), +32 (instr1)
    const int colh = (((tid & 7) << 3)) ^ ((sr & 7) << 3);     // swizzled source col (halfs)
    const int wub = (tid & ~63) * 16;                          // wave-uniform LDS byte base

    // Q fragments (B-operand: col=lr=q), 4 q-frags x 2 d-halves, pre-scaled by 1/sqrt(D)*log2(e)
    f16x8 aq[4][2];
    const half_t cch = (half_t)(0.125f * 1.4426950408889634f);
#pragma unroll
    for (int qf = 0; qf < 4; ++qf)
#pragma unroll
        for (int dh = 0; dh < 2; ++dh) {
            aq[qf][dh] = *reinterpret_cast<const f16x8*>(&Qp[(size_t)(q0 + qf * 16 + lr) * NQKV + dh * 32 + g * 8]);
#pragma unroll
            for (int j = 0; j < 8; ++j) aq[qf][dh][j] = aq[qf][dh][j] * cch;
        }

    // swizzled K-read columns (b128): row = st*16+lr, chunk ^= (lr&7)
    const int swk = (lr & 7) << 3;
    const int cA = (g * 8) ^ swk;          // d-chunk 0
    const int cB = (32 + g * 8) ^ swk;     // d-chunk 1
    // swizzled V-read columns (b64 pairs) for this wave's key-half (ks = kw)
    const int psw = lr & 7;
    const int goff = (g & 1) << 2;
    const int vcol[2] = { (((g >> 1) + 4 * kw + 0) ^ psw) * 8 + goff,
                          (((g >> 1) + 4 * kw + 2) ^ psw) * 8 + goff };

    f32x4 y[4][4];
#pragma unroll
    for (int qf = 0; qf < 4; ++qf)
#pragma unroll
        for (int df = 0; df < 4; ++df) y[qf][df] = (f32x4){0.f, 0.f, 0.f, 0.f};
    float l_[4] = {0.f, 0.f, 0.f, 0.f};

    auto stagebuf = [&](int buf, const half_t* Ks, const half_t* Vs) {
        char* kdst = (char*)&sm.m.K[buf][0] + wub;
        char* vdst = (char*)&sm.m.V[buf][0] + wub;
        load_lds16(Ks, kdst);
        load_lds16(Ks + (size_t)32 * NQKV, kdst + 4096);
        load_lds16(Vs, vdst);
        load_lds16(Vs + (size_t)32 * NT, vdst + 4096);
    };

    const half_t* ksrc = Kp + (size_t)sr * NQKV + colh;
    const half_t* vsrc = Vbase + (size_t)sr * NT + colh;
    stagebuf(0, ksrc, vsrc);
    ksrc += (size_t)64 * NQKV;
    vsrc += 64;
    __syncthreads();
    int cur = 0;
    const int stb = 2 * kw;

    for (int t = 0; t < NT / 64; ++t) {
        if (t < NT / 64 - 1) {
            stagebuf(cur ^ 1, ksrc, vsrc);
            ksrc += (size_t)64 * NQKV;
            vsrc += 64;
        }

        // ---- QK^T (swapped), this wave's 32-key half: s[qf][sl][i], st = stb+sl ----
        f32x4 s[4][2];
#pragma unroll
        for (int qf = 0; qf < 4; ++qf) { s[qf][0] = (f32x4){0.f,0.f,0.f,0.f}; s[qf][1] = (f32x4){0.f,0.f,0.f,0.f}; }
        const half_t* Kc = &sm.m.K[cur][0];
        __builtin_amdgcn_s_setprio(1);
#pragma unroll
        for (int sl = 0; sl < 2; ++sl) {
            const int row = (stb + sl) * 16 + lr;
            f16x8 bk0 = *reinterpret_cast<const f16x8*>(&Kc[row * 64 + cA]);
            s[0][sl] = MFMA16(bk0, aq[0][0], s[0][sl]);
            s[1][sl] = MFMA16(bk0, aq[1][0], s[1][sl]);
            s[2][sl] = MFMA16(bk0, aq[2][0], s[2][sl]);
            s[3][sl] = MFMA16(bk0, aq[3][0], s[3][sl]);
            f16x8 bk1 = *reinterpret_cast<const f16x8*>(&Kc[row * 64 + cB]);
            s[0][sl] = MFMA16(bk1, aq[0][1], s[0][sl]);
            s[1][sl] = MFMA16(bk1, aq[1][1], s[1][sl]);
            s[2][sl] = MFMA16(bk1, aq[2][1], s[2][sl]);
            s[3][sl] = MFMA16(bk1, aq[3][1], s[3][sl]);
        }
        __builtin_amdgcn_s_setprio(0);

        // ---- no-max softmax + lane-local pack: pb[qf] = packed p for this key-half ----
        f16x8 pb[4];
#pragma unroll
        for (int qf = 0; qf < 4; ++qf) {
            float ps = 0.f;
            union { f16x8 v; fp16x2 h[4]; } u;
#pragma unroll
            for (int hs = 0; hs < 2; ++hs) {   // hs: local st within this ks
                const float p0 = __builtin_amdgcn_exp2f(s[qf][hs][0]);
                const float p1 = __builtin_amdgcn_exp2f(s[qf][hs][1]);
                const float p2 = __builtin_amdgcn_exp2f(s[qf][hs][2]);
                const float p3 = __builtin_amdgcn_exp2f(s[qf][hs][3]);
                u.h[2 * hs]     = __builtin_amdgcn_cvt_pkrtz(p0, p1);
                u.h[2 * hs + 1] = __builtin_amdgcn_cvt_pkrtz(p2, p3);
                ps += (p0 + p1) + (p2 + p3);
            }
            pb[qf] = u.v;
            l_[qf] += ps;
        }

        // ---- PV (ks = kw): A = V^T rows, B = pb (register) ----
        const half_t* Vc = &sm.m.V[cur][0];
        __builtin_amdgcn_s_setprio(1);
#pragma unroll
        for (int df = 0; df < 4; ++df) {
            const half_t* vrow = &Vc[(df * 16 + lr) * 64];
            union { f16x8 v; f16x4 q[2]; } va;
            va.q[0] = *reinterpret_cast<const f16x4*>(vrow + vcol[0]);
            va.q[1] = *reinterpret_cast<const f16x4*>(vrow + vcol[1]);
            y[0][df] = MFMA16(va.v, pb[0], y[0][df]);
            y[1][df] = MFMA16(va.v, pb[1], y[1][df]);
            y[2][df] = MFMA16(va.v, pb[2], y[2][df]);
            y[3][df] = MFMA16(va.v, pb[3], y[3][df]);
        }
        __builtin_amdgcn_s_setprio(0);

        __syncthreads();   // drains stage vmcnt + all waves done reading buf[cur]
        cur ^= 1;
    }

    // ---- cross-wave (key-half) reduction: kw=1 publishes y/l, kw=0 combines+stores ----
    if (kw == 1) {
#pragma unroll
        for (int qf = 0; qf < 4; ++qf)
#pragma unroll
            for (int df = 0; df < 4; ++df) {
                const int jb = (qf * 16 + df * 4) ^ ((lane & 7) << 2);   // bank swizzle
                *reinterpret_cast<f32x4*>(&sm.r.y[qw][lane][jb]) = y[qf][df];
            }
#pragma unroll
        for (int qf = 0; qf < 4; ++qf) sm.r.l[qw][lane][qf] = l_[qf];
    }
    __syncthreads();
    if (kw == 0) {
#pragma unroll
        for (int qf = 0; qf < 4; ++qf) {
#pragma unroll
            for (int df = 0; df < 4; ++df) {
                const int jb = (qf * 16 + df * 4) ^ ((lane & 7) << 2);
                const f32x4 yp = *reinterpret_cast<const f32x4*>(&sm.r.y[qw][lane][jb]);
                y[qf][df] += yp;
            }
            float l = l_[qf] + sm.r.l[qw][lane][qf];
            l += __shfl_xor(l, 16);
            l += __shfl_xor(l, 32);
            const float rl = 1.f / l;
            half_t* Yp = Y + (size_t)(b * NT + q0 + qf * 16 + lr) * NC + h * ND + g * 4;
#pragma unroll
            for (int df = 0; df < 4; ++df) {
                union { f16x4 v; fp16x2 hh[2]; } o;
                o.hh[0] = __builtin_amdgcn_cvt_pkrtz(y[qf][df][0] * rl, y[qf][df][1] * rl);
                o.hh[1] = __builtin_amdgcn_cvt_pkrtz(y[qf][df][2] * rl, y[qf][df][3] * rl);
                *reinterpret_cast<f16x4*>(Yp + df * 16) = o.v;
            }
        }
    }
}

extern "C" void kernel_launch(void* const* d_in, const int* in_sizes, int n_in,
                              void* d_out, int out_size, void* d_ws, size_t ws_size,
                              hipStream_t stream) {
    const float* x  = (const float*)d_in[0];
    const float* Wa = (const float*)d_in[1];
    const float* ba = (const float*)d_in[2];
    const float* Wp = (const float*)d_in[3];
    const float* bp = (const float*)d_in[4];
    float* out = (float*)d_out;

    char* ws = (char*)d_ws;
    half_t* xh   = (half_t*)ws; ws += (size_t)NBT * NC * 2;
    half_t* Wat  = (half_t*)ws; ws += (size_t)NQKV * NC * 2;
    half_t* Wpt  = (half_t*)ws; ws += (size_t)NC * NC * 2;
    half_t* qkvh = (half_t*)ws; ws += (size_t)NBT * NQKV * 2;
    half_t* vt   = (half_t*)ws; ws += (size_t)NB * NH * ND * NT * 2;
    half_t* yh   = (half_t*)ws; ws += (size_t)NBT * NC * 2;

    k_prep<<<PREP_BLKS, 256, 0, stream>>>(x, xh, Wa, Wat, Wp, Wpt);
    k_gemm0<<<dim3(NBT / 128, NQKV / 192), 256, 0, stream>>>(xh, Wat, ba, qkvh, vt);
    k_attn<<<dim3(NT / 128, NB * NH), 256, 0, stream>>>(qkvh, vt, yh);
    k_gemm1<<<dim3(NBT / 128, NC / 96), 256, 0, stream>>>(yh, Wpt, bp, out);
}